// Round 16
// baseline (160.788 us; speedup 1.0000x reference)
//
#include <hip/hip_runtime.h>
#include <hip/hip_bf16.h>
#include <stdint.h>

#define HEADS 8
#define DHEAD 64
#define INNER 512
#define QDIM 1024
#define CDIM 768
#define ODIM 1024
#define BATCH 2
#define NQ 4096
#define NKEY 4096

using bf16x8 = __attribute__((ext_vector_type(8))) short;
using f32x4  = __attribute__((ext_vector_type(4))) float;

__device__ __forceinline__ unsigned short f2bf(float x) {
    union { float f; unsigned u; } v; v.f = x;
    unsigned r = v.u + 0x7fffu + ((v.u >> 16) & 1u);   // RTNE
    return (unsigned short)(r >> 16);
}

__device__ __forceinline__ unsigned cvtpk(float a, float b) {
    unsigned r;
    asm("v_cvt_pk_bf16_f32 %0, %1, %2" : "=v"(r) : "v"(a), "v"(b));
    return r;
}

__device__ __forceinline__ float exp2a(float x) {
    float r;
    asm("v_exp_f32 %0, %1" : "=v"(r) : "v"(x));
    return r;
}

typedef const __attribute__((address_space(1))) unsigned int* gptr_t;
typedef __attribute__((address_space(3))) unsigned int* lptr_t;

__device__ __forceinline__ void async16(const void* g, void* l) {
    __builtin_amdgcn_global_load_lds((gptr_t)g, (lptr_t)l, 16, 0, 0);
}

#define SGB __builtin_amdgcn_sched_group_barrier

// ---------------- fp32 -> bf16 convert (vectorized) ----------------
__global__ void k_convert(const float* __restrict__ in, unsigned short* __restrict__ out, int n4) {
    int i = blockIdx.x * blockDim.x + threadIdx.x;
    int stride = gridDim.x * blockDim.x;
    for (; i < n4; i += stride) {
        float4 v = reinterpret_cast<const float4*>(in)[i];
        ushort4 o;
        o.x = f2bf(v.x); o.y = f2bf(v.y); o.z = f2bf(v.z); o.w = f2bf(v.w);
        reinterpret_cast<ushort4*>(out)[i] = o;
    }
}

// ---------------- transpose fp32 [R,C] -> bf16 [C,R] ----------------
__global__ void k_transpose_bf16(const float* __restrict__ in, unsigned short* __restrict__ out,
                                 int R, int C) {
    __shared__ float tile[32][33];
    int c0 = blockIdx.x * 32, r0 = blockIdx.y * 32;
    int tx = threadIdx.x, ty = threadIdx.y;   // block (32,8)
    #pragma unroll
    for (int i = 0; i < 32; i += 8)
        tile[ty + i][tx] = in[(size_t)(r0 + ty + i) * C + c0 + tx];
    __syncthreads();
    #pragma unroll
    for (int i = 0; i < 32; i += 8)
        out[(size_t)(c0 + ty + i) * R + r0 + tx] = f2bf(tile[tx][ty + i]);
}

// ---------------- bf16 MFMA GEMM, 128x64 tile, BK=64, dbuf LDS (R7-proven) ----------------
template <int OUTMODE>
__global__ __launch_bounds__(256) void k_gemm(const unsigned short* __restrict__ A,
                                              const unsigned short* __restrict__ BT,
                                              void* __restrict__ Cout,
                                              const float* __restrict__ bias,
                                              int M, int N, int Kd, float scale) {
    __shared__ alignas(16) unsigned short As[2][128 * 64];
    __shared__ alignas(16) unsigned short Bs[2][64 * 64];
    const int tid = threadIdx.x, lane = tid & 63, w = tid >> 6;
    const int g = lane >> 4, ql = lane & 15;
    const int m0 = blockIdx.x * 128, n0 = blockIdx.y * 64;
    const int wm = (w >> 1) * 64, wn = (w & 1) * 32;
    f32x4 acc[4][2] = {};

    const int srow = tid >> 3;
    const int schunk = ((tid & 7) ^ (srow & 7)) << 3;
    const unsigned short* gA = A + (size_t)(m0 + srow) * Kd + schunk;
    const unsigned short* gB = BT + (size_t)(n0 + srow) * Kd + schunk;

    auto stage = [&](int buf, int kt) {
        char* lA = (char*)As[buf] + (w << 10);
        char* lB = (char*)Bs[buf] + (w << 10);
        async16(gA + kt, lA);
        async16(gA + kt + (size_t)32 * Kd, lA + 4096);
        async16(gA + kt + (size_t)64 * Kd, lA + 8192);
        async16(gA + kt + (size_t)96 * Kd, lA + 12288);
        async16(gB + kt, lB);
        async16(gB + kt + (size_t)32 * Kd, lB + 4096);
    };

#define GCOMP(BUF) { \
        _Pragma("unroll") \
        for (int kk = 0; kk < 2; kk++) { \
            bf16x8 af[4], bfr[2]; \
            _Pragma("unroll") \
            for (int mi = 0; mi < 4; mi++) { \
                int r = wm + mi * 16 + ql; \
                af[mi] = *(const bf16x8*)((const char*)As[BUF] + r * 128 + ((kk * 64 + (g << 4)) ^ ((r & 7) << 4))); \
            } \
            _Pragma("unroll") \
            for (int ni = 0; ni < 2; ni++) { \
                int r = wn + ni * 16 + ql; \
                bfr[ni] = *(const bf16x8*)((const char*)Bs[BUF] + r * 128 + ((kk * 64 + (g << 4)) ^ ((r & 7) << 4))); \
            } \
            _Pragma("unroll") \
            for (int mi = 0; mi < 4; mi++) \
                _Pragma("unroll") \
                for (int ni = 0; ni < 2; ni++) \
                    acc[mi][ni] = __builtin_amdgcn_mfma_f32_16x16x32_bf16(af[mi], bfr[ni], acc[mi][ni], 0, 0, 0); \
        } \
    }

    stage(0, 0);
    for (int kt = 0; kt < Kd; kt += 128) {
        asm volatile("s_waitcnt vmcnt(0)" ::: "memory");
        __builtin_amdgcn_s_barrier();
        __builtin_amdgcn_sched_barrier(0);
        if (kt + 64 < Kd) stage(1, kt + 64);
        GCOMP(0);
        asm volatile("s_waitcnt vmcnt(0)" ::: "memory");
        __builtin_amdgcn_s_barrier();
        __builtin_amdgcn_sched_barrier(0);
        if (kt + 128 < Kd) stage(0, kt + 128);
        GCOMP(1);
    }
#undef GCOMP

    #pragma unroll
    for (int mi = 0; mi < 4; mi++) {
        #pragma unroll
        for (int ni = 0; ni < 2; ni++) {
            int col = n0 + wn + ni * 16 + ql;
            #pragma unroll
            for (int j = 0; j < 4; j++) {
                int row = m0 + wm + mi * 16 + (g << 2) + j;
                float v = acc[mi][ni][j] * scale;
                if (OUTMODE == 0) {
                    ((unsigned short*)Cout)[(size_t)row * N + col] = f2bf(v);
                } else {
                    ((float*)Cout)[(size_t)row * N + col] = v + bias[col];
                }
            }
        }
    }
}

// ---------------- flash attention: R7 body, 4-buffer LDS, barrier every 2 tiles ----------------
// Same compute body as R7 (82 us): swapped QK, rho K-rows, in-reg P, max-free log2
// softmax, SGB interleave. Schedule change only: K(t) in Ks[t&3], V(t) in Vs[t&3];
// body t stages K(t+3), V(t+2); barrier+vmcnt(0) only at EVEN bodies. Every read's
// stage is >=2 bodies old (an even-top barrier always intervenes); every overwrite is
// >=3 bodies after its last read; max inter-wave skew (1 body) touches disjoint slots.
__global__ __launch_bounds__(256, 2) void k_attn(const unsigned short* __restrict__ Q,
                                                 const unsigned short* __restrict__ K,
                                                 const unsigned short* __restrict__ Vt,
                                                 unsigned short* __restrict__ O) {
    __shared__ alignas(16) unsigned short Ks[4][64 * 64];
    __shared__ alignas(16) unsigned short Vs[4][64 * 64];
    const int tid = threadIdx.x, lane = tid & 63, w = tid >> 6;
    const int g = lane >> 4, ql = lane & 15;
    const int q0 = blockIdx.x * 128;
    const int b = blockIdx.y >> 3, h = blockIdx.y & 7;

    const unsigned short* qp = Q + (size_t)(b * NQ + q0 + w * 32 + ql) * INNER
                                 + h * DHEAD + (g << 3);
    bf16x8 qf00 = *(const bf16x8*)qp;
    bf16x8 qf01 = *(const bf16x8*)(qp + 32);
    bf16x8 qf10 = *(const bf16x8*)(qp + 16 * INNER);
    bf16x8 qf11 = *(const bf16x8*)(qp + 16 * INNER + 32);

    f32x4 po0[4] = {}, po1[4] = {};
    float ls0 = 0.f, ls1 = 0.f;
    const f32x4 zero4 = {0.f, 0.f, 0.f, 0.f};

    const int m0 = tid >> 3;
    const int rho0 = ((m0 & 28) << 1) + (m0 & 3);          // rho rows 0..31; rho(m+32)=rho(m)+4
    const int srcslot = ((tid & 7) ^ (m0 & 7)) << 3;       // swizzle pre-applied on source
    const unsigned short* gK = K + (size_t)(b * NKEY + rho0) * INNER + h * DHEAD + srcslot;
    const unsigned short* gV = Vt + (size_t)(h * DHEAD + m0) * (BATCH * NKEY) + b * NKEY + srcslot;

    auto stageK = [&](int slot, int kt) {
        char* lK = (char*)Ks + (slot << 13) + (w << 10);
        async16(gK + (size_t)kt * INNER, lK);
        async16(gK + (size_t)(kt + 4) * INNER, lK + 4096);
    };
    auto stageV = [&](int slot, int kt) {
        char* lV = (char*)Vs + (slot << 13) + (w << 10);
        async16(gV + kt, lV);
        async16(gV + kt + (size_t)32 * (BATCH * NKEY), lV + 4096);
    };

    union pfu { bf16x8 v; unsigned u[4]; };

#define SMCHUNK(MI, SC0, SC1, pA, pB, lsa, lsb) { \
        float a0 = exp2a(SC0[MI][0]), a1 = exp2a(SC0[MI][1]); \
        float a2 = exp2a(SC0[MI][2]), a3 = exp2a(SC0[MI][3]); \
        float b0 = exp2a(SC1[MI][0]), b1 = exp2a(SC1[MI][1]); \
        float b2 = exp2a(SC1[MI][2]), b3 = exp2a(SC1[MI][3]); \
        lsa += (a0 + a1) + (a2 + a3); \
        lsb += (b0 + b1) + (b2 + b3); \
        pA[MI & 1].u[(MI >> 1) * 2 + 0] = cvtpk(a0, a1); \
        pA[MI & 1].u[(MI >> 1) * 2 + 1] = cvtpk(a2, a3); \
        pB[MI & 1].u[(MI >> 1) * 2 + 0] = cvtpk(b0, b1); \
        pB[MI & 1].u[(MI >> 1) * 2 + 1] = cvtpk(b2, b3); \
    }

#define QKM(KBUF, S0, S1) { \
        const char* Kq_ = (const char*)(KBUF); \
        _Pragma("unroll") \
        for (int mi = 0; mi < 4; mi++) { \
            int rK = mi * 16 + ql; \
            int sw = (rK & 7) << 4; \
            bf16x8 kf0 = *(const bf16x8*)(Kq_ + rK * 128 + ((g << 4) ^ sw)); \
            bf16x8 kf1 = *(const bf16x8*)(Kq_ + rK * 128 + ((64 + (g << 4)) ^ sw)); \
            S0[mi] = __builtin_amdgcn_mfma_f32_16x16x32_bf16(kf0, qf00, zero4, 0, 0, 0); \
            S0[mi] = __builtin_amdgcn_mfma_f32_16x16x32_bf16(kf1, qf01, S0[mi], 0, 0, 0); \
            S1[mi] = __builtin_amdgcn_mfma_f32_16x16x32_bf16(kf0, qf10, zero4, 0, 0, 0); \
            S1[mi] = __builtin_amdgcn_mfma_f32_16x16x32_bf16(kf1, qf11, S1[mi], 0, 0, 0); \
        } \
    }

#define PVM(VBUF, pA, pB) { \
        const char* Vp_ = (const char*)(VBUF); \
        bf16x8 vf0[4], vf1[4]; \
        _Pragma("unroll") \
        for (int mi = 0; mi < 4; mi++) { \
            int rV = mi * 16 + ql; \
            int sw = (rV & 7) << 4; \
            vf0[mi] = *(const bf16x8*)(Vp_ + rV * 128 + ((g << 4) ^ sw)); \
            vf1[mi] = *(const bf16x8*)(Vp_ + rV * 128 + ((64 + (g << 4)) ^ sw)); \
        } \
        _Pragma("unroll") \
        for (int mi = 0; mi < 4; mi++) { \
            po0[mi] = __builtin_amdgcn_mfma_f32_16x16x32_bf16(vf0[mi], pA[0].v, po0[mi], 0, 0, 0); \
            po0[mi] = __builtin_amdgcn_mfma_f32_16x16x32_bf16(vf1[mi], pA[1].v, po0[mi], 0, 0, 0); \
            po1[mi] = __builtin_amdgcn_mfma_f32_16x16x32_bf16(vf0[mi], pB[0].v, po1[mi], 0, 0, 0); \
            po1[mi] = __builtin_amdgcn_mfma_f32_16x16x32_bf16(vf1[mi], pB[1].v, po1[mi], 0, 0, 0); \
        } \
    }

// ABODY(T, BAR): reads K(T+1) from Ks[(T+1)&3], V(T) from Vs[T&3];
// stages K(T+3)->Ks[(T+3)&3], V(T+2)->Vs[(T+2)&3]; barrier only when BAR.
#define ABODY(T, BAR, SC0, SC1, SN0, SN1, DO_K, DO_V) { \
        if (BAR) { \
            asm volatile("s_waitcnt vmcnt(0)" ::: "memory"); \
            __builtin_amdgcn_s_barrier(); \
            __builtin_amdgcn_sched_barrier(0); \
        } \
        if (DO_K) stageK(((T) + 3) & 3, ((T) + 3) * 64); \
        if (DO_V) stageV(((T) + 2) & 3, ((T) + 2) * 64); \
        const char* Kbase = (const char*)Ks + (((((T) + 1)) & 3) << 13); \
        const char* Vbase = (const char*)Vs + (((T) & 3) << 13); \
        bf16x8 kf0[4], kf1[4]; \
        _Pragma("unroll") \
        for (int mi = 0; mi < 4; mi++) { \
            int rK = mi * 16 + ql; \
            int sw = (rK & 7) << 4; \
            kf0[mi] = *(const bf16x8*)(Kbase + rK * 128 + ((g << 4) ^ sw)); \
            kf1[mi] = *(const bf16x8*)(Kbase + rK * 128 + ((64 + (g << 4)) ^ sw)); \
        } \
        __builtin_amdgcn_sched_group_barrier(0x100, 8, 0); \
        pfu pA[2], pB[2]; \
        float lsa = 0.f, lsb = 0.f; \
        _Pragma("unroll") \
        for (int mi = 0; mi < 4; mi++) { \
            SMCHUNK(mi, SC0, SC1, pA, pB, lsa, lsb); \
            __builtin_amdgcn_sched_group_barrier(0x2, 18, 0); \
            SN0[mi] = __builtin_amdgcn_mfma_f32_16x16x32_bf16(kf0[mi], qf00, zero4, 0, 0, 0); \
            SN0[mi] = __builtin_amdgcn_mfma_f32_16x16x32_bf16(kf1[mi], qf01, SN0[mi], 0, 0, 0); \
            SN1[mi] = __builtin_amdgcn_mfma_f32_16x16x32_bf16(kf0[mi], qf10, zero4, 0, 0, 0); \
            SN1[mi] = __builtin_amdgcn_mfma_f32_16x16x32_bf16(kf1[mi], qf11, SN1[mi], 0, 0, 0); \
            __builtin_amdgcn_sched_group_barrier(0x8, 4, 0); \
        } \
        ls0 += lsa; ls1 += lsb; \
        __builtin_amdgcn_s_setprio(1); \
        PVM(Vbase, pA, pB); \
        __builtin_amdgcn_sched_group_barrier(0x100, 8, 0); \
        __builtin_amdgcn_sched_group_barrier(0x8, 16, 0); \
        __builtin_amdgcn_s_setprio(0); \
    }

    f32x4 sE0[4], sE1[4], sO0[4], sO1[4];

    // prologue: K(0),K(1),K(2),V(0),V(1) in flight; drain; QK(0) from Ks[0]
    stageK(0, 0); stageK(1, 64); stageK(2, 128);
    stageV(0, 0); stageV(1, 64);
    asm volatile("s_waitcnt vmcnt(0)" ::: "memory");
    __builtin_amdgcn_s_barrier();
    __builtin_amdgcn_sched_barrier(0);
    QKM(Ks[0], sE0, sE1);

    for (int t = 0; t < 60; t += 2) {
        ABODY(t, 1, sE0, sE1, sO0, sO1, 1, 1);
        ABODY(t + 1, 0, sO0, sO1, sE0, sE1, 1, 1);
    }
    ABODY(60, 1, sE0, sE1, sO0, sO1, 1, 1);   // stages K(63), V(62)
    ABODY(61, 0, sO0, sO1, sE0, sE1, 0, 1);   // stages V(63)
    ABODY(62, 1, sE0, sE1, sO0, sO1, 0, 0);   // QK(63) -> sO

    // tail: tile 63 (scores in sO, V(63) in Vs[3]; staged body 61, drained at top of 62)
    asm volatile("s_waitcnt vmcnt(0)" ::: "memory");
    __builtin_amdgcn_s_barrier();
    __builtin_amdgcn_sched_barrier(0);
    {
        pfu pA[2], pB[2];
        float lsa = 0.f, lsb = 0.f;
        #pragma unroll
        for (int mi = 0; mi < 4; mi++) {
            SMCHUNK(mi, sO0, sO1, pA, pB, lsa, lsb);
        }
        ls0 += lsa; ls1 += lsb;
        PVM(Vs[3], pA, pB);
    }

    // epilogue
    ls0 += __shfl_xor(ls0, 16); ls0 += __shfl_xor(ls0, 32);
    ls1 += __shfl_xor(ls1, 16); ls1 += __shfl_xor(ls1, 32);
    float inv0 = 1.0f / ls0, inv1 = 1.0f / ls1;
    unsigned short* op = O + (size_t)(b * NQ + q0 + w * 32 + ql) * INNER + h * DHEAD + (g << 2);
    #pragma unroll
    for (int mi = 0; mi < 4; mi++) {
        uint2 uu;
        uu.x = cvtpk(po0[mi][0] * inv0, po0[mi][1] * inv0);
        uu.y = cvtpk(po0[mi][2] * inv0, po0[mi][3] * inv0);
        *(uint2*)(op + mi * 16) = uu;
        uint2 vv;
        vv.x = cvtpk(po1[mi][0] * inv1, po1[mi][1] * inv1);
        vv.y = cvtpk(po1[mi][2] * inv1, po1[mi][3] * inv1);
        *(uint2*)(op + 16 * INNER + mi * 16) = vv;
    }
#undef ABODY
#undef PVM
#undef QKM
#undef SMCHUNK
}

extern "C" void kernel_launch(void* const* d_in, const int* in_sizes, int n_in,
                              void* d_out, int out_size, void* d_ws, size_t ws_size,
                              hipStream_t stream) {
    const float* x     = (const float*)d_in[0];
    const float* ctx   = (const float*)d_in[1];
    const float* w_q   = (const float*)d_in[2];
    const float* w_k   = (const float*)d_in[3];
    const float* w_v   = (const float*)d_in[4];
    const float* w_out = (const float*)d_in[5];
    const float* b_out = (const float*)d_in[6];
    float* out = (float*)d_out;

    char* ws = (char*)d_ws;
    size_t off = 0;
    auto alloc = [&](size_t bytes) { void* p = ws + off; off += (bytes + 255) & ~(size_t)255; return p; };
    unsigned short* xb  = (unsigned short*)alloc((size_t)BATCH * NQ * QDIM * 2);
    unsigned short* cb  = (unsigned short*)alloc((size_t)BATCH * NKEY * CDIM * 2);
    unsigned short* wqT = (unsigned short*)alloc((size_t)INNER * QDIM * 2);
    unsigned short* wkT = (unsigned short*)alloc((size_t)INNER * CDIM * 2);
    unsigned short* wvT = (unsigned short*)alloc((size_t)INNER * CDIM * 2);
    unsigned short* woT = (unsigned short*)alloc((size_t)ODIM * INNER * 2);
    unsigned short* Qb  = (unsigned short*)alloc((size_t)BATCH * NQ * INNER * 2);
    unsigned short* Kb  = (unsigned short*)alloc((size_t)BATCH * NKEY * INNER * 2);
    unsigned short* Vtb = (unsigned short*)alloc((size_t)INNER * BATCH * NKEY * 2);
    unsigned short* Ob  = (unsigned short*)alloc((size_t)BATCH * NQ * INNER * 2);

    k_convert<<<2048, 256, 0, stream>>>(x, xb, BATCH * NQ * QDIM / 4);
    k_convert<<<2048, 256, 0, stream>>>(ctx, cb, BATCH * NKEY * CDIM / 4);

    dim3 tb(32, 8);
    k_transpose_bf16<<<dim3(INNER / 32, QDIM / 32), tb, 0, stream>>>(w_q, wqT, QDIM, INNER);
    k_transpose_bf16<<<dim3(INNER / 32, CDIM / 32), tb, 0, stream>>>(w_k, wkT, CDIM, INNER);
    k_transpose_bf16<<<dim3(INNER / 32, CDIM / 32), tb, 0, stream>>>(w_v, wvT, CDIM, INNER);
    k_transpose_bf16<<<dim3(ODIM / 32, INNER / 32), tb, 0, stream>>>(w_out, woT, INNER, ODIM);

    // Q = (x @ w_q) * (1/8)*log2(e)  -> scores in log2 domain
    k_gemm<0><<<dim3(8192 / 128, 512 / 64), 256, 0, stream>>>(xb, wqT, Qb, nullptr, 8192, 512, 1024, 0.1803368801111204f);
    // K = ctx @ w_k
    k_gemm<0><<<dim3(8192 / 128, 512 / 64), 256, 0, stream>>>(cb, wkT, Kb, nullptr, 8192, 512, 768, 1.0f);
    // Vt = (ctx @ w_v)^T = wvT @ ctx^T
    k_gemm<0><<<dim3(512 / 128, 8192 / 64), 256, 0, stream>>>(wvT, cb, Vtb, nullptr, 512, 8192, 768, 1.0f);

    k_attn<<<dim3(NQ / 128, BATCH * HEADS), 256, 0, stream>>>(Qb, Kb, Vtb, Ob);

    // out = O @ w_out + b_out
    k_gemm<1><<<dim3(8192 / 128, 1024 / 64), 256, 0, stream>>>(Ob, woT, out, b_out, 8192, 1024, 512, 1.0f);
}

// Round 17
// 149.951 us; speedup vs baseline: 1.0723x; 1.0723x over previous
//
#include <hip/hip_runtime.h>
#include <hip/hip_bf16.h>
#include <stdint.h>

#define HEADS 8
#define DHEAD 64
#define INNER 512
#define QDIM 1024
#define CDIM 768
#define ODIM 1024
#define BATCH 2
#define NQ 4096
#define NKEY 4096

using bf16x8 = __attribute__((ext_vector_type(8))) short;
using f32x4  = __attribute__((ext_vector_type(4))) float;

__device__ __forceinline__ unsigned short f2bf(float x) {
    union { float f; unsigned u; } v; v.f = x;
    unsigned r = v.u + 0x7fffu + ((v.u >> 16) & 1u);   // RTNE
    return (unsigned short)(r >> 16);
}

__device__ __forceinline__ unsigned cvtpk(float a, float b) {
    unsigned r;
    asm("v_cvt_pk_bf16_f32 %0, %1, %2" : "=v"(r) : "v"(a), "v"(b));
    return r;
}

__device__ __forceinline__ float exp2a(float x) {
    float r;
    asm("v_exp_f32 %0, %1" : "=v"(r) : "v"(x));
    return r;
}

typedef const __attribute__((address_space(1))) unsigned int* gptr_t;
typedef __attribute__((address_space(3))) unsigned int* lptr_t;

__device__ __forceinline__ void async16(const void* g, void* l) {
    __builtin_amdgcn_global_load_lds((gptr_t)g, (lptr_t)l, 16, 0, 0);
}

#define SGB __builtin_amdgcn_sched_group_barrier

// ---------------- fp32 -> bf16 convert: x and ctx in ONE launch ----------------
__global__ void k_convert2(const float* __restrict__ in0, unsigned short* __restrict__ out0, int n0,
                           const float* __restrict__ in1, unsigned short* __restrict__ out1, int n1) {
    int i = blockIdx.x * blockDim.x + threadIdx.x;
    int stride = gridDim.x * blockDim.x;
    int ntot = n0 + n1;
    for (; i < ntot; i += stride) {
        const float* in = (i < n0) ? in0 : in1;
        unsigned short* out = (i < n0) ? out0 : out1;
        int j = (i < n0) ? i : i - n0;
        float4 v = reinterpret_cast<const float4*>(in)[j];
        ushort4 o;
        o.x = f2bf(v.x); o.y = f2bf(v.y); o.z = f2bf(v.z); o.w = f2bf(v.w);
        reinterpret_cast<ushort4*>(out)[j] = o;
    }
}

// ---------------- transpose all 4 weights fp32 [R,C] -> bf16 [C,R] in ONE launch ----------------
__global__ void k_transpose_all(const float* __restrict__ in0, unsigned short* __restrict__ out0,
                                const float* __restrict__ in1, unsigned short* __restrict__ out1,
                                const float* __restrict__ in2, unsigned short* __restrict__ out2,
                                const float* __restrict__ in3, unsigned short* __restrict__ out3) {
    __shared__ float tile[32][33];
    const int z = blockIdx.z;
    const int R = (z == 0) ? QDIM : (z == 3) ? INNER : CDIM;
    const int C = (z == 3) ? ODIM : INNER;
    const float* in = (z == 0) ? in0 : (z == 1) ? in1 : (z == 2) ? in2 : in3;
    unsigned short* out = (z == 0) ? out0 : (z == 1) ? out1 : (z == 2) ? out2 : out3;
    int c0 = blockIdx.x * 32, r0 = blockIdx.y * 32;
    if (c0 >= C || r0 >= R) return;
    int tx = threadIdx.x, ty = threadIdx.y;   // block (32,8)
    #pragma unroll
    for (int i = 0; i < 32; i += 8)
        tile[ty + i][tx] = in[(size_t)(r0 + ty + i) * C + c0 + tx];
    __syncthreads();
    #pragma unroll
    for (int i = 0; i < 32; i += 8)
        out[(size_t)(c0 + ty + i) * R + r0 + tx] = f2bf(tile[tx][ty + i]);
}

// ---------------- bf16 MFMA GEMM, 128x64 tile, BK=64, dbuf LDS (R7-proven) ----------------
template <int OUTMODE>
__global__ __launch_bounds__(256) void k_gemm(const unsigned short* __restrict__ A,
                                              const unsigned short* __restrict__ BT,
                                              void* __restrict__ Cout,
                                              const float* __restrict__ bias,
                                              int M, int N, int Kd, float scale) {
    __shared__ alignas(16) unsigned short As[2][128 * 64];
    __shared__ alignas(16) unsigned short Bs[2][64 * 64];
    const int tid = threadIdx.x, lane = tid & 63, w = tid >> 6;
    const int g = lane >> 4, ql = lane & 15;
    const int m0 = blockIdx.x * 128, n0 = blockIdx.y * 64;
    const int wm = (w >> 1) * 64, wn = (w & 1) * 32;
    f32x4 acc[4][2] = {};

    const int srow = tid >> 3;
    const int schunk = ((tid & 7) ^ (srow & 7)) << 3;
    const unsigned short* gA = A + (size_t)(m0 + srow) * Kd + schunk;
    const unsigned short* gB = BT + (size_t)(n0 + srow) * Kd + schunk;

    auto stage = [&](int buf, int kt) {
        char* lA = (char*)As[buf] + (w << 10);
        char* lB = (char*)Bs[buf] + (w << 10);
        async16(gA + kt, lA);
        async16(gA + kt + (size_t)32 * Kd, lA + 4096);
        async16(gA + kt + (size_t)64 * Kd, lA + 8192);
        async16(gA + kt + (size_t)96 * Kd, lA + 12288);
        async16(gB + kt, lB);
        async16(gB + kt + (size_t)32 * Kd, lB + 4096);
    };

#define GCOMP(BUF) { \
        _Pragma("unroll") \
        for (int kk = 0; kk < 2; kk++) { \
            bf16x8 af[4], bfr[2]; \
            _Pragma("unroll") \
            for (int mi = 0; mi < 4; mi++) { \
                int r = wm + mi * 16 + ql; \
                af[mi] = *(const bf16x8*)((const char*)As[BUF] + r * 128 + ((kk * 64 + (g << 4)) ^ ((r & 7) << 4))); \
            } \
            _Pragma("unroll") \
            for (int ni = 0; ni < 2; ni++) { \
                int r = wn + ni * 16 + ql; \
                bfr[ni] = *(const bf16x8*)((const char*)Bs[BUF] + r * 128 + ((kk * 64 + (g << 4)) ^ ((r & 7) << 4))); \
            } \
            _Pragma("unroll") \
            for (int mi = 0; mi < 4; mi++) \
                _Pragma("unroll") \
                for (int ni = 0; ni < 2; ni++) \
                    acc[mi][ni] = __builtin_amdgcn_mfma_f32_16x16x32_bf16(af[mi], bfr[ni], acc[mi][ni], 0, 0, 0); \
        } \
    }

    stage(0, 0);
    for (int kt = 0; kt < Kd; kt += 128) {
        asm volatile("s_waitcnt vmcnt(0)" ::: "memory");
        __builtin_amdgcn_s_barrier();
        __builtin_amdgcn_sched_barrier(0);
        if (kt + 64 < Kd) stage(1, kt + 64);
        GCOMP(0);
        asm volatile("s_waitcnt vmcnt(0)" ::: "memory");
        __builtin_amdgcn_s_barrier();
        __builtin_amdgcn_sched_barrier(0);
        if (kt + 128 < Kd) stage(0, kt + 128);
        GCOMP(1);
    }
#undef GCOMP

    #pragma unroll
    for (int mi = 0; mi < 4; mi++) {
        #pragma unroll
        for (int ni = 0; ni < 2; ni++) {
            int col = n0 + wn + ni * 16 + ql;
            #pragma unroll
            for (int j = 0; j < 4; j++) {
                int row = m0 + wm + mi * 16 + (g << 2) + j;
                float v = acc[mi][ni][j] * scale;
                if (OUTMODE == 0) {
                    ((unsigned short*)Cout)[(size_t)row * N + col] = f2bf(v);
                } else {
                    ((float*)Cout)[(size_t)row * N + col] = v + bias[col];
                }
            }
        }
    }
}

// ---------------- flash attention: R7-proven body (82 us, verified) ----------------
__global__ __launch_bounds__(256, 2) void k_attn(const unsigned short* __restrict__ Q,
                                                 const unsigned short* __restrict__ K,
                                                 const unsigned short* __restrict__ Vt,
                                                 unsigned short* __restrict__ O) {
    __shared__ alignas(16) unsigned short Ks[2][64 * 64];
    __shared__ alignas(16) unsigned short Vs[2][64 * 64];
    const int tid = threadIdx.x, lane = tid & 63, w = tid >> 6;
    const int g = lane >> 4, ql = lane & 15;
    const int q0 = blockIdx.x * 128;
    const int b = blockIdx.y >> 3, h = blockIdx.y & 7;

    const unsigned short* qp = Q + (size_t)(b * NQ + q0 + w * 32 + ql) * INNER
                                 + h * DHEAD + (g << 3);
    bf16x8 qf00 = *(const bf16x8*)qp;
    bf16x8 qf01 = *(const bf16x8*)(qp + 32);
    bf16x8 qf10 = *(const bf16x8*)(qp + 16 * INNER);
    bf16x8 qf11 = *(const bf16x8*)(qp + 16 * INNER + 32);

    f32x4 po0[4] = {}, po1[4] = {};
    float ls0 = 0.f, ls1 = 0.f;
    const f32x4 zero4 = {0.f, 0.f, 0.f, 0.f};

    const int m0 = tid >> 3;
    const int rho0 = ((m0 & 28) << 1) + (m0 & 3);          // rho rows 0..31; rho(m+32)=rho(m)+4
    const int srcslot = ((tid & 7) ^ (m0 & 7)) << 3;       // swizzle pre-applied on source
    const unsigned short* gK = K + (size_t)(b * NKEY + rho0) * INNER + h * DHEAD + srcslot;
    const unsigned short* gV = Vt + (size_t)(h * DHEAD + m0) * (BATCH * NKEY) + b * NKEY + srcslot;

    auto stageK = [&](int nb, int kt) {
        char* lK = (char*)Ks[nb] + (w << 10);
        async16(gK + (size_t)kt * INNER, lK);
        async16(gK + (size_t)(kt + 4) * INNER, lK + 4096);
    };
    auto stageV = [&](int nb, int kt) {
        char* lV = (char*)Vs[nb] + (w << 10);
        async16(gV + kt, lV);
        async16(gV + kt + (size_t)32 * (BATCH * NKEY), lV + 4096);
    };

    union pfu { bf16x8 v; unsigned u[4]; };

#define SMCHUNK(MI, SC0, SC1, pA, pB, lsa, lsb) { \
        float a0 = exp2a(SC0[MI][0]), a1 = exp2a(SC0[MI][1]); \
        float a2 = exp2a(SC0[MI][2]), a3 = exp2a(SC0[MI][3]); \
        float b0 = exp2a(SC1[MI][0]), b1 = exp2a(SC1[MI][1]); \
        float b2 = exp2a(SC1[MI][2]), b3 = exp2a(SC1[MI][3]); \
        lsa += (a0 + a1) + (a2 + a3); \
        lsb += (b0 + b1) + (b2 + b3); \
        pA[MI & 1].u[(MI >> 1) * 2 + 0] = cvtpk(a0, a1); \
        pA[MI & 1].u[(MI >> 1) * 2 + 1] = cvtpk(a2, a3); \
        pB[MI & 1].u[(MI >> 1) * 2 + 0] = cvtpk(b0, b1); \
        pB[MI & 1].u[(MI >> 1) * 2 + 1] = cvtpk(b2, b3); \
    }

#define QKM(KBUF, S0, S1) { \
        const char* Kb_ = (const char*)(KBUF); \
        _Pragma("unroll") \
        for (int mi = 0; mi < 4; mi++) { \
            int rK = mi * 16 + ql; \
            int sw = (rK & 7) << 4; \
            bf16x8 kf0 = *(const bf16x8*)(Kb_ + rK * 128 + ((g << 4) ^ sw)); \
            bf16x8 kf1 = *(const bf16x8*)(Kb_ + rK * 128 + ((64 + (g << 4)) ^ sw)); \
            S0[mi] = __builtin_amdgcn_mfma_f32_16x16x32_bf16(kf0, qf00, zero4, 0, 0, 0); \
            S0[mi] = __builtin_amdgcn_mfma_f32_16x16x32_bf16(kf1, qf01, S0[mi], 0, 0, 0); \
            S1[mi] = __builtin_amdgcn_mfma_f32_16x16x32_bf16(kf0, qf10, zero4, 0, 0, 0); \
            S1[mi] = __builtin_amdgcn_mfma_f32_16x16x32_bf16(kf1, qf11, S1[mi], 0, 0, 0); \
        } \
    }

#define PVM(VBUF, pA, pB) { \
        const char* Vb_ = (const char*)(VBUF); \
        bf16x8 vf0[4], vf1[4]; \
        _Pragma("unroll") \
        for (int mi = 0; mi < 4; mi++) { \
            int rV = mi * 16 + ql; \
            int sw = (rV & 7) << 4; \
            vf0[mi] = *(const bf16x8*)(Vb_ + rV * 128 + ((g << 4) ^ sw)); \
            vf1[mi] = *(const bf16x8*)(Vb_ + rV * 128 + ((64 + (g << 4)) ^ sw)); \
        } \
        _Pragma("unroll") \
        for (int mi = 0; mi < 4; mi++) { \
            po0[mi] = __builtin_amdgcn_mfma_f32_16x16x32_bf16(vf0[mi], pA[0].v, po0[mi], 0, 0, 0); \
            po0[mi] = __builtin_amdgcn_mfma_f32_16x16x32_bf16(vf1[mi], pA[1].v, po0[mi], 0, 0, 0); \
            po1[mi] = __builtin_amdgcn_mfma_f32_16x16x32_bf16(vf0[mi], pB[0].v, po1[mi], 0, 0, 0); \
            po1[mi] = __builtin_amdgcn_mfma_f32_16x16x32_bf16(vf1[mi], pB[1].v, po1[mi], 0, 0, 0); \
        } \
    }

#define ABODY(T, CUR, SC0, SC1, SN0, SN1, DO_K, DO_V) { \
        asm volatile("s_waitcnt vmcnt(0)" ::: "memory"); \
        __builtin_amdgcn_s_barrier(); \
        __builtin_amdgcn_sched_barrier(0); \
        if (DO_K) stageK(CUR, (T + 2) * 64); \
        if (DO_V) stageV(CUR ^ 1, (T + 1) * 64); \
        const char* Kb_ = (const char*)Ks[CUR ^ 1]; \
        bf16x8 kf0[4], kf1[4]; \
        _Pragma("unroll") \
        for (int mi = 0; mi < 4; mi++) { \
            int rK = mi * 16 + ql; \
            int sw = (rK & 7) << 4; \
            kf0[mi] = *(const bf16x8*)(Kb_ + rK * 128 + ((g << 4) ^ sw)); \
            kf1[mi] = *(const bf16x8*)(Kb_ + rK * 128 + ((64 + (g << 4)) ^ sw)); \
        } \
        __builtin_amdgcn_sched_group_barrier(0x100, 8, 0); \
        pfu pA[2], pB[2]; \
        float lsa = 0.f, lsb = 0.f; \
        _Pragma("unroll") \
        for (int mi = 0; mi < 4; mi++) { \
            SMCHUNK(mi, SC0, SC1, pA, pB, lsa, lsb); \
            __builtin_amdgcn_sched_group_barrier(0x2, 18, 0); \
            SN0[mi] = __builtin_amdgcn_mfma_f32_16x16x32_bf16(kf0[mi], qf00, zero4, 0, 0, 0); \
            SN0[mi] = __builtin_amdgcn_mfma_f32_16x16x32_bf16(kf1[mi], qf01, SN0[mi], 0, 0, 0); \
            SN1[mi] = __builtin_amdgcn_mfma_f32_16x16x32_bf16(kf0[mi], qf10, zero4, 0, 0, 0); \
            SN1[mi] = __builtin_amdgcn_mfma_f32_16x16x32_bf16(kf1[mi], qf11, SN1[mi], 0, 0, 0); \
            __builtin_amdgcn_sched_group_barrier(0x8, 4, 0); \
        } \
        ls0 += lsa; ls1 += lsb; \
        __builtin_amdgcn_s_setprio(1); \
        PVM(Vs[CUR], pA, pB); \
        __builtin_amdgcn_sched_group_barrier(0x100, 8, 0); \
        __builtin_amdgcn_sched_group_barrier(0x8, 16, 0); \
        __builtin_amdgcn_s_setprio(0); \
    }

    f32x4 sE0[4], sE1[4], sO0[4], sO1[4];

    // prologue: K(0),V(0),K(1) in flight; wait oldest 4 (K0+V0), then QK(0)
    stageK(0, 0); stageV(0, 0); stageK(1, 64);
    asm volatile("s_waitcnt vmcnt(2)" ::: "memory");
    __builtin_amdgcn_s_barrier();
    __builtin_amdgcn_sched_barrier(0);
    QKM(Ks[0], sE0, sE1);

    for (int t = 0; t < 62; t += 2) {
        ABODY(t, 0, sE0, sE1, sO0, sO1, 1, 1);
        ABODY(t + 1, 1, sO0, sO1, sE0, sE1, 1, 1);
    }
    ABODY(62, 0, sE0, sE1, sO0, sO1, 0, 1);

    // tail: tile 63 (scores in sO, V(63) in Vs[1])
    asm volatile("s_waitcnt vmcnt(0)" ::: "memory");
    __builtin_amdgcn_s_barrier();
    __builtin_amdgcn_sched_barrier(0);
    {
        pfu pA[2], pB[2];
        float lsa = 0.f, lsb = 0.f;
        #pragma unroll
        for (int mi = 0; mi < 4; mi++) {
            SMCHUNK(mi, sO0, sO1, pA, pB, lsa, lsb);
        }
        ls0 += lsa; ls1 += lsb;
        PVM(Vs[1], pA, pB);
    }

    // epilogue
    ls0 += __shfl_xor(ls0, 16); ls0 += __shfl_xor(ls0, 32);
    ls1 += __shfl_xor(ls1, 16); ls1 += __shfl_xor(ls1, 32);
    float inv0 = 1.0f / ls0, inv1 = 1.0f / ls1;
    unsigned short* op = O + (size_t)(b * NQ + q0 + w * 32 + ql) * INNER + h * DHEAD + (g << 2);
    #pragma unroll
    for (int mi = 0; mi < 4; mi++) {
        uint2 uu;
        uu.x = cvtpk(po0[mi][0] * inv0, po0[mi][1] * inv0);
        uu.y = cvtpk(po0[mi][2] * inv0, po0[mi][3] * inv0);
        *(uint2*)(op + mi * 16) = uu;
        uint2 vv;
        vv.x = cvtpk(po1[mi][0] * inv1, po1[mi][1] * inv1);
        vv.y = cvtpk(po1[mi][2] * inv1, po1[mi][3] * inv1);
        *(uint2*)(op + 16 * INNER + mi * 16) = vv;
    }
#undef ABODY
#undef PVM
#undef QKM
#undef SMCHUNK
}

extern "C" void kernel_launch(void* const* d_in, const int* in_sizes, int n_in,
                              void* d_out, int out_size, void* d_ws, size_t ws_size,
                              hipStream_t stream) {
    const float* x     = (const float*)d_in[0];
    const float* ctx   = (const float*)d_in[1];
    const float* w_q   = (const float*)d_in[2];
    const float* w_k   = (const float*)d_in[3];
    const float* w_v   = (const float*)d_in[4];
    const float* w_out = (const float*)d_in[5];
    const float* b_out = (const float*)d_in[6];
    float* out = (float*)d_out;

    char* ws = (char*)d_ws;
    size_t off = 0;
    auto alloc = [&](size_t bytes) { void* p = ws + off; off += (bytes + 255) & ~(size_t)255; return p; };
    unsigned short* xb  = (unsigned short*)alloc((size_t)BATCH * NQ * QDIM * 2);
    unsigned short* cb  = (unsigned short*)alloc((size_t)BATCH * NKEY * CDIM * 2);
    unsigned short* wqT = (unsigned short*)alloc((size_t)INNER * QDIM * 2);
    unsigned short* wkT = (unsigned short*)alloc((size_t)INNER * CDIM * 2);
    unsigned short* wvT = (unsigned short*)alloc((size_t)INNER * CDIM * 2);
    unsigned short* woT = (unsigned short*)alloc((size_t)ODIM * INNER * 2);
    unsigned short* Qb  = (unsigned short*)alloc((size_t)BATCH * NQ * INNER * 2);
    unsigned short* Kb  = (unsigned short*)alloc((size_t)BATCH * NKEY * INNER * 2);
    unsigned short* Vtb = (unsigned short*)alloc((size_t)INNER * BATCH * NKEY * 2);
    unsigned short* Ob  = (unsigned short*)alloc((size_t)BATCH * NQ * INNER * 2);

    // one launch: convert x and ctx to bf16
    k_convert2<<<2048, 256, 0, stream>>>(x, xb, BATCH * NQ * QDIM / 4,
                                         ctx, cb, BATCH * NKEY * CDIM / 4);

    // one launch: transpose+convert all 4 weight matrices
    k_transpose_all<<<dim3(32, 32, 4), dim3(32, 8), 0, stream>>>(
        w_q, wqT, w_k, wkT, w_v, wvT, w_out, woT);

    // Q = (x @ w_q) * (1/8)*log2(e)  -> scores in log2 domain
    k_gemm<0><<<dim3(8192 / 128, 512 / 64), 256, 0, stream>>>(xb, wqT, Qb, nullptr, 8192, 512, 1024, 0.1803368801111204f);
    // K = ctx @ w_k
    k_gemm<0><<<dim3(8192 / 128, 512 / 64), 256, 0, stream>>>(cb, wkT, Kb, nullptr, 8192, 512, 768, 1.0f);
    // Vt = (ctx @ w_v)^T = wvT @ ctx^T
    k_gemm<0><<<dim3(512 / 128, 8192 / 64), 256, 0, stream>>>(wvT, cb, Vtb, nullptr, 512, 8192, 768, 1.0f);

    k_attn<<<dim3(NQ / 128, BATCH * HEADS), 256, 0, stream>>>(Qb, Kb, Vtb, Ob);

    // out = O @ w_out + b_out
    k_gemm<1><<<dim3(8192 / 128, 1024 / 64), 256, 0, stream>>>(Ob, woT, out, b_out, 8192, 1024, 512, 1.0f);
}

// Round 18
// 139.901 us; speedup vs baseline: 1.1493x; 1.0718x over previous
//
#include <hip/hip_runtime.h>
#include <hip/hip_bf16.h>
#include <stdint.h>

#define HEADS 8
#define DHEAD 64
#define INNER 512
#define QDIM 1024
#define CDIM 768
#define ODIM 1024
#define BATCH 2
#define NQ 4096
#define NKEY 4096

using bf16x8 = __attribute__((ext_vector_type(8))) short;
using f32x4  = __attribute__((ext_vector_type(4))) float;

__device__ __forceinline__ unsigned short f2bf(float x) {
    union { float f; unsigned u; } v; v.f = x;
    unsigned r = v.u + 0x7fffu + ((v.u >> 16) & 1u);   // RTNE
    return (unsigned short)(r >> 16);
}

__device__ __forceinline__ unsigned cvtpk(float a, float b) {
    unsigned r;
    asm("v_cvt_pk_bf16_f32 %0, %1, %2" : "=v"(r) : "v"(a), "v"(b));
    return r;
}

__device__ __forceinline__ float exp2a(float x) {
    float r;
    asm("v_exp_f32 %0, %1" : "=v"(r) : "v"(x));
    return r;
}

typedef const __attribute__((address_space(1))) unsigned int* gptr_t;
typedef __attribute__((address_space(3))) unsigned int* lptr_t;

__device__ __forceinline__ void async16(const void* g, void* l) {
    __builtin_amdgcn_global_load_lds((gptr_t)g, (lptr_t)l, 16, 0, 0);
}

#define SGB __builtin_amdgcn_sched_group_barrier

// ---------------- fp32 -> bf16 convert: x and ctx in ONE launch ----------------
__global__ void k_convert2(const float* __restrict__ in0, unsigned short* __restrict__ out0, int n0,
                           const float* __restrict__ in1, unsigned short* __restrict__ out1, int n1) {
    int i = blockIdx.x * blockDim.x + threadIdx.x;
    int stride = gridDim.x * blockDim.x;
    int ntot = n0 + n1;
    for (; i < ntot; i += stride) {
        const float* in = (i < n0) ? in0 : in1;
        unsigned short* out = (i < n0) ? out0 : out1;
        int j = (i < n0) ? i : i - n0;
        float4 v = reinterpret_cast<const float4*>(in)[j];
        ushort4 o;
        o.x = f2bf(v.x); o.y = f2bf(v.y); o.z = f2bf(v.z); o.w = f2bf(v.w);
        reinterpret_cast<ushort4*>(out)[j] = o;
    }
}

// ---------------- transpose all 4 weights fp32 [R,C] -> bf16 [C,R] in ONE launch ----------------
__global__ void k_transpose_all(const float* __restrict__ in0, unsigned short* __restrict__ out0,
                                const float* __restrict__ in1, unsigned short* __restrict__ out1,
                                const float* __restrict__ in2, unsigned short* __restrict__ out2,
                                const float* __restrict__ in3, unsigned short* __restrict__ out3) {
    __shared__ float tile[32][33];
    const int z = blockIdx.z;
    const int R = (z == 0) ? QDIM : (z == 3) ? INNER : CDIM;
    const int C = (z == 3) ? ODIM : INNER;
    const float* in = (z == 0) ? in0 : (z == 1) ? in1 : (z == 2) ? in2 : in3;
    unsigned short* out = (z == 0) ? out0 : (z == 1) ? out1 : (z == 2) ? out2 : out3;
    int c0 = blockIdx.x * 32, r0 = blockIdx.y * 32;
    if (c0 >= C || r0 >= R) return;
    int tx = threadIdx.x, ty = threadIdx.y;   // block (32,8)
    #pragma unroll
    for (int i = 0; i < 32; i += 8)
        tile[ty + i][tx] = in[(size_t)(r0 + ty + i) * C + c0 + tx];
    __syncthreads();
    #pragma unroll
    for (int i = 0; i < 32; i += 8)
        out[(size_t)(c0 + ty + i) * R + r0 + tx] = f2bf(tile[tx][ty + i]);
}

// ---------------- GEMM compute body (shared by merged-QKV and out GEMM) ----------------
#define GEMM_BODY(A_, BT_, COUT_, BIAS_, N_, KD_, SCALE_, OUTMODE_)                                  \
    {                                                                                                \
        const int tid = threadIdx.x, lane = tid & 63, w = tid >> 6;                                  \
        const int g = lane >> 4, ql = lane & 15;                                                     \
        const int wm = (w >> 1) * 64, wn = (w & 1) * 32;                                             \
        f32x4 acc[4][2] = {};                                                                        \
        const int srow = tid >> 3;                                                                   \
        const int schunk = ((tid & 7) ^ (srow & 7)) << 3;                                            \
        const unsigned short* gA = (A_) + (size_t)(m0 + srow) * (KD_) + schunk;                      \
        const unsigned short* gB = (BT_) + (size_t)(n0 + srow) * (KD_) + schunk;                     \
        auto stage = [&](int buf, int kt) {                                                          \
            char* lA = (char*)As[buf] + (w << 10);                                                   \
            char* lB = (char*)Bs[buf] + (w << 10);                                                   \
            async16(gA + kt, lA);                                                                    \
            async16(gA + kt + (size_t)32 * (KD_), lA + 4096);                                        \
            async16(gA + kt + (size_t)64 * (KD_), lA + 8192);                                        \
            async16(gA + kt + (size_t)96 * (KD_), lA + 12288);                                       \
            async16(gB + kt, lB);                                                                    \
            async16(gB + kt + (size_t)32 * (KD_), lB + 4096);                                        \
        };                                                                                           \
        stage(0, 0);                                                                                 \
        for (int kt = 0; kt < (KD_); kt += 128) {                                                    \
            asm volatile("s_waitcnt vmcnt(0)" ::: "memory");                                         \
            __builtin_amdgcn_s_barrier();                                                            \
            __builtin_amdgcn_sched_barrier(0);                                                       \
            if (kt + 64 < (KD_)) stage(1, kt + 64);                                                  \
            GCOMP(0);                                                                                \
            asm volatile("s_waitcnt vmcnt(0)" ::: "memory");                                         \
            __builtin_amdgcn_s_barrier();                                                            \
            __builtin_amdgcn_sched_barrier(0);                                                       \
            if (kt + 128 < (KD_)) stage(0, kt + 128);                                                \
            GCOMP(1);                                                                                \
        }                                                                                            \
        _Pragma("unroll")                                                                            \
        for (int mi = 0; mi < 4; mi++) {                                                             \
            _Pragma("unroll")                                                                        \
            for (int ni = 0; ni < 2; ni++) {                                                         \
                int col = n0 + wn + ni * 16 + ql;                                                    \
                _Pragma("unroll")                                                                    \
                for (int j = 0; j < 4; j++) {                                                        \
                    int row = m0 + wm + mi * 16 + (g << 2) + j;                                      \
                    float v = acc[mi][ni][j] * (SCALE_);                                             \
                    if (OUTMODE_ == 0) {                                                             \
                        ((unsigned short*)(COUT_))[(size_t)row * (N_) + col] = f2bf(v);              \
                    } else {                                                                         \
                        ((float*)(COUT_))[(size_t)row * (N_) + col] = v + (BIAS_)[col];              \
                    }                                                                                \
                }                                                                                    \
            }                                                                                        \
        }                                                                                            \
    }

#define GCOMP(BUF) { \
        _Pragma("unroll") \
        for (int kk = 0; kk < 2; kk++) { \
            bf16x8 af[4], bfr[2]; \
            _Pragma("unroll") \
            for (int mi = 0; mi < 4; mi++) { \
                int r = wm + mi * 16 + ql; \
                af[mi] = *(const bf16x8*)((const char*)As[BUF] + r * 128 + ((kk * 64 + (g << 4)) ^ ((r & 7) << 4))); \
            } \
            _Pragma("unroll") \
            for (int ni = 0; ni < 2; ni++) { \
                int r = wn + ni * 16 + ql; \
                bfr[ni] = *(const bf16x8*)((const char*)Bs[BUF] + r * 128 + ((kk * 64 + (g << 4)) ^ ((r & 7) << 4))); \
            } \
            _Pragma("unroll") \
            for (int mi = 0; mi < 4; mi++) \
                _Pragma("unroll") \
                for (int ni = 0; ni < 2; ni++) \
                    acc[mi][ni] = __builtin_amdgcn_mfma_f32_16x16x32_bf16(af[mi], bfr[ni], acc[mi][ni], 0, 0, 0); \
        } \
    }

// ---------------- merged Q/K/Vt GEMM: one dispatch, z selects operands ----------------
// z=0: Qb = xb @ wqT^T * scale    (M=8192, N=512,  Kd=1024), blocks 64x8
// z=1: Kb = cb @ wkT^T            (M=8192, N=512,  Kd=768),  blocks 64x8
// z=2: Vtb = wvT @ cb^T           (M=512,  N=8192, Kd=768),  4x128 remapped from 64x8
// 1536 blocks, 48KB LDS -> 3 blocks/CU: cross-GEMM blocks co-reside, stalls overlap.
__global__ __launch_bounds__(256) void k_gemm_qkv(const unsigned short* __restrict__ xb,
                                                  const unsigned short* __restrict__ cb,
                                                  const unsigned short* __restrict__ wqT,
                                                  const unsigned short* __restrict__ wkT,
                                                  const unsigned short* __restrict__ wvT,
                                                  unsigned short* __restrict__ Qb,
                                                  unsigned short* __restrict__ Kb,
                                                  unsigned short* __restrict__ Vtb) {
    __shared__ alignas(16) unsigned short As[2][128 * 64];
    __shared__ alignas(16) unsigned short Bs[2][64 * 64];
    const int z = blockIdx.z;
    const unsigned short* A  = (z == 0) ? xb : (z == 1) ? cb : wvT;
    const unsigned short* BT = (z == 0) ? wqT : (z == 1) ? wkT : cb;
    unsigned short* Cout     = (z == 0) ? Qb : (z == 1) ? Kb : Vtb;
    const int Kd = (z == 0) ? 1024 : 768;
    const int N  = (z == 2) ? 8192 : 512;
    const float scale = (z == 0) ? 0.1803368801111204f : 1.0f;
    int bx = blockIdx.x, by = blockIdx.y;
    if (z == 2) { int flat = by * 64 + bx; bx = flat & 3; by = flat >> 2; }
    const int m0 = bx * 128, n0 = by * 64;
    GEMM_BODY(A, BT, Cout, (const float*)nullptr, N, Kd, scale, 0);
}

// ---------------- out GEMM: fp32 + bias (R7-proven body) ----------------
__global__ __launch_bounds__(256) void k_gemm_out(const unsigned short* __restrict__ A,
                                                  const unsigned short* __restrict__ BT,
                                                  float* __restrict__ Cout,
                                                  const float* __restrict__ bias) {
    __shared__ alignas(16) unsigned short As[2][128 * 64];
    __shared__ alignas(16) unsigned short Bs[2][64 * 64];
    const int m0 = blockIdx.x * 128, n0 = blockIdx.y * 64;
    GEMM_BODY(A, BT, Cout, bias, ODIM, INNER, 1.0f, 1);
}

// ---------------- flash attention: R7-proven body (82 us, verified) ----------------
__global__ __launch_bounds__(256, 2) void k_attn(const unsigned short* __restrict__ Q,
                                                 const unsigned short* __restrict__ K,
                                                 const unsigned short* __restrict__ Vt,
                                                 unsigned short* __restrict__ O) {
    __shared__ alignas(16) unsigned short Ks[2][64 * 64];
    __shared__ alignas(16) unsigned short Vs[2][64 * 64];
    const int tid = threadIdx.x, lane = tid & 63, w = tid >> 6;
    const int g = lane >> 4, ql = lane & 15;
    const int q0 = blockIdx.x * 128;
    const int b = blockIdx.y >> 3, h = blockIdx.y & 7;

    const unsigned short* qp = Q + (size_t)(b * NQ + q0 + w * 32 + ql) * INNER
                                 + h * DHEAD + (g << 3);
    bf16x8 qf00 = *(const bf16x8*)qp;
    bf16x8 qf01 = *(const bf16x8*)(qp + 32);
    bf16x8 qf10 = *(const bf16x8*)(qp + 16 * INNER);
    bf16x8 qf11 = *(const bf16x8*)(qp + 16 * INNER + 32);

    f32x4 po0[4] = {}, po1[4] = {};
    float ls0 = 0.f, ls1 = 0.f;
    const f32x4 zero4 = {0.f, 0.f, 0.f, 0.f};

    const int m0 = tid >> 3;
    const int rho0 = ((m0 & 28) << 1) + (m0 & 3);          // rho rows 0..31; rho(m+32)=rho(m)+4
    const int srcslot = ((tid & 7) ^ (m0 & 7)) << 3;       // swizzle pre-applied on source
    const unsigned short* gK = K + (size_t)(b * NKEY + rho0) * INNER + h * DHEAD + srcslot;
    const unsigned short* gV = Vt + (size_t)(h * DHEAD + m0) * (BATCH * NKEY) + b * NKEY + srcslot;

    auto stageK = [&](int nb, int kt) {
        char* lK = (char*)Ks[nb] + (w << 10);
        async16(gK + (size_t)kt * INNER, lK);
        async16(gK + (size_t)(kt + 4) * INNER, lK + 4096);
    };
    auto stageV = [&](int nb, int kt) {
        char* lV = (char*)Vs[nb] + (w << 10);
        async16(gV + kt, lV);
        async16(gV + kt + (size_t)32 * (BATCH * NKEY), lV + 4096);
    };

    union pfu { bf16x8 v; unsigned u[4]; };

#define SMCHUNK(MI, SC0, SC1, pA, pB, lsa, lsb) { \
        float a0 = exp2a(SC0[MI][0]), a1 = exp2a(SC0[MI][1]); \
        float a2 = exp2a(SC0[MI][2]), a3 = exp2a(SC0[MI][3]); \
        float b0 = exp2a(SC1[MI][0]), b1 = exp2a(SC1[MI][1]); \
        float b2 = exp2a(SC1[MI][2]), b3 = exp2a(SC1[MI][3]); \
        lsa += (a0 + a1) + (a2 + a3); \
        lsb += (b0 + b1) + (b2 + b3); \
        pA[MI & 1].u[(MI >> 1) * 2 + 0] = cvtpk(a0, a1); \
        pA[MI & 1].u[(MI >> 1) * 2 + 1] = cvtpk(a2, a3); \
        pB[MI & 1].u[(MI >> 1) * 2 + 0] = cvtpk(b0, b1); \
        pB[MI & 1].u[(MI >> 1) * 2 + 1] = cvtpk(b2, b3); \
    }

#define QKM(KBUF, S0, S1) { \
        const char* Kb_ = (const char*)(KBUF); \
        _Pragma("unroll") \
        for (int mi = 0; mi < 4; mi++) { \
            int rK = mi * 16 + ql; \
            int sw = (rK & 7) << 4; \
            bf16x8 kf0 = *(const bf16x8*)(Kb_ + rK * 128 + ((g << 4) ^ sw)); \
            bf16x8 kf1 = *(const bf16x8*)(Kb_ + rK * 128 + ((64 + (g << 4)) ^ sw)); \
            S0[mi] = __builtin_amdgcn_mfma_f32_16x16x32_bf16(kf0, qf00, zero4, 0, 0, 0); \
            S0[mi] = __builtin_amdgcn_mfma_f32_16x16x32_bf16(kf1, qf01, S0[mi], 0, 0, 0); \
            S1[mi] = __builtin_amdgcn_mfma_f32_16x16x32_bf16(kf0, qf10, zero4, 0, 0, 0); \
            S1[mi] = __builtin_amdgcn_mfma_f32_16x16x32_bf16(kf1, qf11, S1[mi], 0, 0, 0); \
        } \
    }

#define PVM(VBUF, pA, pB) { \
        const char* Vb_ = (const char*)(VBUF); \
        bf16x8 vf0[4], vf1[4]; \
        _Pragma("unroll") \
        for (int mi = 0; mi < 4; mi++) { \
            int rV = mi * 16 + ql; \
            int sw = (rV & 7) << 4; \
            vf0[mi] = *(const bf16x8*)(Vb_ + rV * 128 + ((g << 4) ^ sw)); \
            vf1[mi] = *(const bf16x8*)(Vb_ + rV * 128 + ((64 + (g << 4)) ^ sw)); \
        } \
        _Pragma("unroll") \
        for (int mi = 0; mi < 4; mi++) { \
            po0[mi] = __builtin_amdgcn_mfma_f32_16x16x32_bf16(vf0[mi], pA[0].v, po0[mi], 0, 0, 0); \
            po0[mi] = __builtin_amdgcn_mfma_f32_16x16x32_bf16(vf1[mi], pA[1].v, po0[mi], 0, 0, 0); \
            po1[mi] = __builtin_amdgcn_mfma_f32_16x16x32_bf16(vf0[mi], pB[0].v, po1[mi], 0, 0, 0); \
            po1[mi] = __builtin_amdgcn_mfma_f32_16x16x32_bf16(vf1[mi], pB[1].v, po1[mi], 0, 0, 0); \
        } \
    }

#define ABODY(T, CUR, SC0, SC1, SN0, SN1, DO_K, DO_V) { \
        asm volatile("s_waitcnt vmcnt(0)" ::: "memory"); \
        __builtin_amdgcn_s_barrier(); \
        __builtin_amdgcn_sched_barrier(0); \
        if (DO_K) stageK(CUR, (T + 2) * 64); \
        if (DO_V) stageV(CUR ^ 1, (T + 1) * 64); \
        const char* Kb_ = (const char*)Ks[CUR ^ 1]; \
        bf16x8 kf0[4], kf1[4]; \
        _Pragma("unroll") \
        for (int mi = 0; mi < 4; mi++) { \
            int rK = mi * 16 + ql; \
            int sw = (rK & 7) << 4; \
            kf0[mi] = *(const bf16x8*)(Kb_ + rK * 128 + ((g << 4) ^ sw)); \
            kf1[mi] = *(const bf16x8*)(Kb_ + rK * 128 + ((64 + (g << 4)) ^ sw)); \
        } \
        __builtin_amdgcn_sched_group_barrier(0x100, 8, 0); \
        pfu pA[2], pB[2]; \
        float lsa = 0.f, lsb = 0.f; \
        _Pragma("unroll") \
        for (int mi = 0; mi < 4; mi++) { \
            SMCHUNK(mi, SC0, SC1, pA, pB, lsa, lsb); \
            __builtin_amdgcn_sched_group_barrier(0x2, 18, 0); \
            SN0[mi] = __builtin_amdgcn_mfma_f32_16x16x32_bf16(kf0[mi], qf00, zero4, 0, 0, 0); \
            SN0[mi] = __builtin_amdgcn_mfma_f32_16x16x32_bf16(kf1[mi], qf01, SN0[mi], 0, 0, 0); \
            SN1[mi] = __builtin_amdgcn_mfma_f32_16x16x32_bf16(kf0[mi], qf10, zero4, 0, 0, 0); \
            SN1[mi] = __builtin_amdgcn_mfma_f32_16x16x32_bf16(kf1[mi], qf11, SN1[mi], 0, 0, 0); \
            __builtin_amdgcn_sched_group_barrier(0x8, 4, 0); \
        } \
        ls0 += lsa; ls1 += lsb; \
        __builtin_amdgcn_s_setprio(1); \
        PVM(Vs[CUR], pA, pB); \
        __builtin_amdgcn_sched_group_barrier(0x100, 8, 0); \
        __builtin_amdgcn_sched_group_barrier(0x8, 16, 0); \
        __builtin_amdgcn_s_setprio(0); \
    }

    f32x4 sE0[4], sE1[4], sO0[4], sO1[4];

    // prologue: K(0),V(0),K(1) in flight; wait oldest 4 (K0+V0), then QK(0)
    stageK(0, 0); stageV(0, 0); stageK(1, 64);
    asm volatile("s_waitcnt vmcnt(2)" ::: "memory");
    __builtin_amdgcn_s_barrier();
    __builtin_amdgcn_sched_barrier(0);
    QKM(Ks[0], sE0, sE1);

    for (int t = 0; t < 62; t += 2) {
        ABODY(t, 0, sE0, sE1, sO0, sO1, 1, 1);
        ABODY(t + 1, 1, sO0, sO1, sE0, sE1, 1, 1);
    }
    ABODY(62, 0, sE0, sE1, sO0, sO1, 0, 1);

    // tail: tile 63 (scores in sO, V(63) in Vs[1])
    asm volatile("s_waitcnt vmcnt(0)" ::: "memory");
    __builtin_amdgcn_s_barrier();
    __builtin_amdgcn_sched_barrier(0);
    {
        pfu pA[2], pB[2];
        float lsa = 0.f, lsb = 0.f;
        #pragma unroll
        for (int mi = 0; mi < 4; mi++) {
            SMCHUNK(mi, sO0, sO1, pA, pB, lsa, lsb);
        }
        ls0 += lsa; ls1 += lsb;
        PVM(Vs[1], pA, pB);
    }

    // epilogue
    ls0 += __shfl_xor(ls0, 16); ls0 += __shfl_xor(ls0, 32);
    ls1 += __shfl_xor(ls1, 16); ls1 += __shfl_xor(ls1, 32);
    float inv0 = 1.0f / ls0, inv1 = 1.0f / ls1;
    unsigned short* op = O + (size_t)(b * NQ + q0 + w * 32 + ql) * INNER + h * DHEAD + (g << 2);
    #pragma unroll
    for (int mi = 0; mi < 4; mi++) {
        uint2 uu;
        uu.x = cvtpk(po0[mi][0] * inv0, po0[mi][1] * inv0);
        uu.y = cvtpk(po0[mi][2] * inv0, po0[mi][3] * inv0);
        *(uint2*)(op + mi * 16) = uu;
        uint2 vv;
        vv.x = cvtpk(po1[mi][0] * inv1, po1[mi][1] * inv1);
        vv.y = cvtpk(po1[mi][2] * inv1, po1[mi][3] * inv1);
        *(uint2*)(op + 16 * INNER + mi * 16) = vv;
    }
#undef ABODY
#undef PVM
#undef QKM
#undef SMCHUNK
}

extern "C" void kernel_launch(void* const* d_in, const int* in_sizes, int n_in,
                              void* d_out, int out_size, void* d_ws, size_t ws_size,
                              hipStream_t stream) {
    const float* x     = (const float*)d_in[0];
    const float* ctx   = (const float*)d_in[1];
    const float* w_q   = (const float*)d_in[2];
    const float* w_k   = (const float*)d_in[3];
    const float* w_v   = (const float*)d_in[4];
    const float* w_out = (const float*)d_in[5];
    const float* b_out = (const float*)d_in[6];
    float* out = (float*)d_out;

    char* ws = (char*)d_ws;
    size_t off = 0;
    auto alloc = [&](size_t bytes) { void* p = ws + off; off += (bytes + 255) & ~(size_t)255; return p; };
    unsigned short* xb  = (unsigned short*)alloc((size_t)BATCH * NQ * QDIM * 2);
    unsigned short* cb  = (unsigned short*)alloc((size_t)BATCH * NKEY * CDIM * 2);
    unsigned short* wqT = (unsigned short*)alloc((size_t)INNER * QDIM * 2);
    unsigned short* wkT = (unsigned short*)alloc((size_t)INNER * CDIM * 2);
    unsigned short* wvT = (unsigned short*)alloc((size_t)INNER * CDIM * 2);
    unsigned short* woT = (unsigned short*)alloc((size_t)ODIM * INNER * 2);
    unsigned short* Qb  = (unsigned short*)alloc((size_t)BATCH * NQ * INNER * 2);
    unsigned short* Kb  = (unsigned short*)alloc((size_t)BATCH * NKEY * INNER * 2);
    unsigned short* Vtb = (unsigned short*)alloc((size_t)INNER * BATCH * NKEY * 2);
    unsigned short* Ob  = (unsigned short*)alloc((size_t)BATCH * NQ * INNER * 2);

    // one launch: convert x and ctx to bf16
    k_convert2<<<2048, 256, 0, stream>>>(x, xb, BATCH * NQ * QDIM / 4,
                                         ctx, cb, BATCH * NKEY * CDIM / 4);

    // one launch: transpose+convert all 4 weight matrices
    k_transpose_all<<<dim3(32, 32, 4), dim3(32, 8), 0, stream>>>(
        w_q, wqT, w_k, wkT, w_v, wvT, w_out, woT);

    // one launch: Q, K, Vt GEMMs (z-selected), 1536 blocks co-resident
    k_gemm_qkv<<<dim3(64, 8, 3), 256, 0, stream>>>(xb, cb, wqT, wkT, wvT, Qb, Kb, Vtb);

    k_attn<<<dim3(NQ / 128, BATCH * HEADS), 256, 0, stream>>>(Qb, Kb, Vtb, Ob);

    // out = O @ w_out + b_out
    k_gemm_out<<<dim3(8192 / 128, 1024 / 64), 256, 0, stream>>>(Ob, woT, out, b_out);
}

// Round 19
// 138.173 us; speedup vs baseline: 1.1637x; 1.0125x over previous
//
#include <hip/hip_runtime.h>
#include <hip/hip_bf16.h>
#include <stdint.h>

#define HEADS 8
#define DHEAD 64
#define INNER 512
#define QDIM 1024
#define CDIM 768
#define ODIM 1024
#define BATCH 2
#define NQ 4096
#define NKEY 4096

using bf16x8 = __attribute__((ext_vector_type(8))) short;
using f32x4  = __attribute__((ext_vector_type(4))) float;

__device__ __forceinline__ unsigned short f2bf(float x) {
    union { float f; unsigned u; } v; v.f = x;
    unsigned r = v.u + 0x7fffu + ((v.u >> 16) & 1u);   // RTNE
    return (unsigned short)(r >> 16);
}

__device__ __forceinline__ unsigned cvtpk(float a, float b) {
    unsigned r;
    asm("v_cvt_pk_bf16_f32 %0, %1, %2" : "=v"(r) : "v"(a), "v"(b));
    return r;
}

__device__ __forceinline__ float exp2a(float x) {
    float r;
    asm("v_exp_f32 %0, %1" : "=v"(r) : "v"(x));
    return r;
}

typedef const __attribute__((address_space(1))) unsigned int* gptr_t;
typedef __attribute__((address_space(3))) unsigned int* lptr_t;

__device__ __forceinline__ void async16(const void* g, void* l) {
    __builtin_amdgcn_global_load_lds((gptr_t)g, (lptr_t)l, 16, 0, 0);
}

#define SGB __builtin_amdgcn_sched_group_barrier

// ---------------- prep: convert x/ctx AND transpose all 4 weights, ONE launch ----------------
// z<4: transpose weight z (32x32 tiles, early-out past bounds).
// z=4: grid-stride bf16 convert of x then ctx (flattened 256-thread blocks).
__global__ void k_prep(const float* __restrict__ x, unsigned short* __restrict__ xb, int n0,
                       const float* __restrict__ ctx, unsigned short* __restrict__ cb, int n1,
                       const float* __restrict__ in0, unsigned short* __restrict__ out0,
                       const float* __restrict__ in1, unsigned short* __restrict__ out1,
                       const float* __restrict__ in2, unsigned short* __restrict__ out2,
                       const float* __restrict__ in3, unsigned short* __restrict__ out3) {
    __shared__ float tile[32][33];
    const int z = blockIdx.z;
    if (z == 4) {
        int flatb = blockIdx.y * gridDim.x + blockIdx.x;
        int t = threadIdx.y * 32 + threadIdx.x;
        int i = flatb * 256 + t;
        int stride = gridDim.x * gridDim.y * 256;
        int ntot = n0 + n1;
        for (; i < ntot; i += stride) {
            const float* in = (i < n0) ? x : ctx;
            unsigned short* out = (i < n0) ? xb : cb;
            int j = (i < n0) ? i : i - n0;
            float4 v = reinterpret_cast<const float4*>(in)[j];
            ushort4 o;
            o.x = f2bf(v.x); o.y = f2bf(v.y); o.z = f2bf(v.z); o.w = f2bf(v.w);
            reinterpret_cast<ushort4*>(out)[j] = o;
        }
        return;
    }
    const int R = (z == 0) ? QDIM : (z == 3) ? INNER : CDIM;
    const int C = (z == 3) ? ODIM : INNER;
    const float* in = (z == 0) ? in0 : (z == 1) ? in1 : (z == 2) ? in2 : in3;
    unsigned short* out = (z == 0) ? out0 : (z == 1) ? out1 : (z == 2) ? out2 : out3;
    int c0 = blockIdx.x * 32, r0 = blockIdx.y * 32;
    if (c0 >= C || r0 >= R) return;
    int tx = threadIdx.x, ty = threadIdx.y;   // block (32,8)
    #pragma unroll
    for (int i = 0; i < 32; i += 8)
        tile[ty + i][tx] = in[(size_t)(r0 + ty + i) * C + c0 + tx];
    __syncthreads();
    #pragma unroll
    for (int i = 0; i < 32; i += 8)
        out[(size_t)(c0 + ty + i) * R + r0 + tx] = f2bf(tile[tx][ty + i]);
}

// ---------------- GEMM compute body (shared by merged-QKV and out GEMM) ----------------
#define GEMM_BODY(A_, BT_, COUT_, BIAS_, N_, KD_, SCALE_, OUTMODE_)                                  \
    {                                                                                                \
        const int tid = threadIdx.x, lane = tid & 63, w = tid >> 6;                                  \
        const int g = lane >> 4, ql = lane & 15;                                                     \
        const int wm = (w >> 1) * 64, wn = (w & 1) * 32;                                             \
        f32x4 acc[4][2] = {};                                                                        \
        const int srow = tid >> 3;                                                                   \
        const int schunk = ((tid & 7) ^ (srow & 7)) << 3;                                            \
        const unsigned short* gA = (A_) + (size_t)(m0 + srow) * (KD_) + schunk;                      \
        const unsigned short* gB = (BT_) + (size_t)(n0 + srow) * (KD_) + schunk;                     \
        auto stage = [&](int buf, int kt) {                                                          \
            char* lA = (char*)As[buf] + (w << 10);                                                   \
            char* lB = (char*)Bs[buf] + (w << 10);                                                   \
            async16(gA + kt, lA);                                                                    \
            async16(gA + kt + (size_t)32 * (KD_), lA + 4096);                                        \
            async16(gA + kt + (size_t)64 * (KD_), lA + 8192);                                        \
            async16(gA + kt + (size_t)96 * (KD_), lA + 12288);                                       \
            async16(gB + kt, lB);                                                                    \
            async16(gB + kt + (size_t)32 * (KD_), lB + 4096);                                        \
        };                                                                                           \
        stage(0, 0);                                                                                 \
        for (int kt = 0; kt < (KD_); kt += 128) {                                                    \
            asm volatile("s_waitcnt vmcnt(0)" ::: "memory");                                         \
            __builtin_amdgcn_s_barrier();                                                            \
            __builtin_amdgcn_sched_barrier(0);                                                       \
            if (kt + 64 < (KD_)) stage(1, kt + 64);                                                  \
            GCOMP(0);                                                                                \
            asm volatile("s_waitcnt vmcnt(0)" ::: "memory");                                         \
            __builtin_amdgcn_s_barrier();                                                            \
            __builtin_amdgcn_sched_barrier(0);                                                       \
            if (kt + 128 < (KD_)) stage(0, kt + 128);                                                \
            GCOMP(1);                                                                                \
        }                                                                                            \
        _Pragma("unroll")                                                                            \
        for (int mi = 0; mi < 4; mi++) {                                                             \
            _Pragma("unroll")                                                                        \
            for (int ni = 0; ni < 2; ni++) {                                                         \
                int col = n0 + wn + ni * 16 + ql;                                                    \
                _Pragma("unroll")                                                                    \
                for (int j = 0; j < 4; j++) {                                                        \
                    int row = m0 + wm + mi * 16 + (g << 2) + j;                                      \
                    float v = acc[mi][ni][j] * (SCALE_);                                             \
                    if (OUTMODE_ == 0) {                                                             \
                        ((unsigned short*)(COUT_))[(size_t)row * (N_) + col] = f2bf(v);              \
                    } else {                                                                         \
                        ((float*)(COUT_))[(size_t)row * (N_) + col] = v + (BIAS_)[col];              \
                    }                                                                                \
                }                                                                                    \
            }                                                                                        \
        }                                                                                            \
    }

#define GCOMP(BUF) { \
        _Pragma("unroll") \
        for (int kk = 0; kk < 2; kk++) { \
            bf16x8 af[4], bfr[2]; \
            _Pragma("unroll") \
            for (int mi = 0; mi < 4; mi++) { \
                int r = wm + mi * 16 + ql; \
                af[mi] = *(const bf16x8*)((const char*)As[BUF] + r * 128 + ((kk * 64 + (g << 4)) ^ ((r & 7) << 4))); \
            } \
            _Pragma("unroll") \
            for (int ni = 0; ni < 2; ni++) { \
                int r = wn + ni * 16 + ql; \
                bfr[ni] = *(const bf16x8*)((const char*)Bs[BUF] + r * 128 + ((kk * 64 + (g << 4)) ^ ((r & 7) << 4))); \
            } \
            _Pragma("unroll") \
            for (int mi = 0; mi < 4; mi++) \
                _Pragma("unroll") \
                for (int ni = 0; ni < 2; ni++) \
                    acc[mi][ni] = __builtin_amdgcn_mfma_f32_16x16x32_bf16(af[mi], bfr[ni], acc[mi][ni], 0, 0, 0); \
        } \
    }

// ---------------- merged Q/K/Vt GEMM: one dispatch, z selects operands ----------------
__global__ __launch_bounds__(256) void k_gemm_qkv(const unsigned short* __restrict__ xb,
                                                  const unsigned short* __restrict__ cb,
                                                  const unsigned short* __restrict__ wqT,
                                                  const unsigned short* __restrict__ wkT,
                                                  const unsigned short* __restrict__ wvT,
                                                  unsigned short* __restrict__ Qb,
                                                  unsigned short* __restrict__ Kb,
                                                  unsigned short* __restrict__ Vtb) {
    __shared__ alignas(16) unsigned short As[2][128 * 64];
    __shared__ alignas(16) unsigned short Bs[2][64 * 64];
    const int z = blockIdx.z;
    const unsigned short* A  = (z == 0) ? xb : (z == 1) ? cb : wvT;
    const unsigned short* BT = (z == 0) ? wqT : (z == 1) ? wkT : cb;
    unsigned short* Cout     = (z == 0) ? Qb : (z == 1) ? Kb : Vtb;
    const int Kd = (z == 0) ? 1024 : 768;
    const int N  = (z == 2) ? 8192 : 512;
    const float scale = (z == 0) ? 0.1803368801111204f : 1.0f;
    int bx = blockIdx.x, by = blockIdx.y;
    if (z == 2) { int flat = by * 64 + bx; bx = flat & 3; by = flat >> 2; }
    const int m0 = bx * 128, n0 = by * 64;
    GEMM_BODY(A, BT, Cout, (const float*)nullptr, N, Kd, scale, 0);
}

// ---------------- out GEMM: fp32 + bias (R7-proven body) ----------------
__global__ __launch_bounds__(256) void k_gemm_out(const unsigned short* __restrict__ A,
                                                  const unsigned short* __restrict__ BT,
                                                  float* __restrict__ Cout,
                                                  const float* __restrict__ bias) {
    __shared__ alignas(16) unsigned short As[2][128 * 64];
    __shared__ alignas(16) unsigned short Bs[2][64 * 64];
    const int m0 = blockIdx.x * 128, n0 = blockIdx.y * 64;
    GEMM_BODY(A, BT, Cout, bias, ODIM, INNER, 1.0f, 1);
}

// ---------------- flash attention: R7-proven body (82 us, verified) ----------------
__global__ __launch_bounds__(256, 2) void k_attn(const unsigned short* __restrict__ Q,
                                                 const unsigned short* __restrict__ K,
                                                 const unsigned short* __restrict__ Vt,
                                                 unsigned short* __restrict__ O) {
    __shared__ alignas(16) unsigned short Ks[2][64 * 64];
    __shared__ alignas(16) unsigned short Vs[2][64 * 64];
    const int tid = threadIdx.x, lane = tid & 63, w = tid >> 6;
    const int g = lane >> 4, ql = lane & 15;
    const int q0 = blockIdx.x * 128;
    const int b = blockIdx.y >> 3, h = blockIdx.y & 7;

    const unsigned short* qp = Q + (size_t)(b * NQ + q0 + w * 32 + ql) * INNER
                                 + h * DHEAD + (g << 3);
    bf16x8 qf00 = *(const bf16x8*)qp;
    bf16x8 qf01 = *(const bf16x8*)(qp + 32);
    bf16x8 qf10 = *(const bf16x8*)(qp + 16 * INNER);
    bf16x8 qf11 = *(const bf16x8*)(qp + 16 * INNER + 32);

    f32x4 po0[4] = {}, po1[4] = {};
    float ls0 = 0.f, ls1 = 0.f;
    const f32x4 zero4 = {0.f, 0.f, 0.f, 0.f};

    const int m0 = tid >> 3;
    const int rho0 = ((m0 & 28) << 1) + (m0 & 3);          // rho rows 0..31; rho(m+32)=rho(m)+4
    const int srcslot = ((tid & 7) ^ (m0 & 7)) << 3;       // swizzle pre-applied on source
    const unsigned short* gK = K + (size_t)(b * NKEY + rho0) * INNER + h * DHEAD + srcslot;
    const unsigned short* gV = Vt + (size_t)(h * DHEAD + m0) * (BATCH * NKEY) + b * NKEY + srcslot;

    auto stageK = [&](int nb, int kt) {
        char* lK = (char*)Ks[nb] + (w << 10);
        async16(gK + (size_t)kt * INNER, lK);
        async16(gK + (size_t)(kt + 4) * INNER, lK + 4096);
    };
    auto stageV = [&](int nb, int kt) {
        char* lV = (char*)Vs[nb] + (w << 10);
        async16(gV + kt, lV);
        async16(gV + kt + (size_t)32 * (BATCH * NKEY), lV + 4096);
    };

    union pfu { bf16x8 v; unsigned u[4]; };

#define SMCHUNK(MI, SC0, SC1, pA, pB, lsa, lsb) { \
        float a0 = exp2a(SC0[MI][0]), a1 = exp2a(SC0[MI][1]); \
        float a2 = exp2a(SC0[MI][2]), a3 = exp2a(SC0[MI][3]); \
        float b0 = exp2a(SC1[MI][0]), b1 = exp2a(SC1[MI][1]); \
        float b2 = exp2a(SC1[MI][2]), b3 = exp2a(SC1[MI][3]); \
        lsa += (a0 + a1) + (a2 + a3); \
        lsb += (b0 + b1) + (b2 + b3); \
        pA[MI & 1].u[(MI >> 1) * 2 + 0] = cvtpk(a0, a1); \
        pA[MI & 1].u[(MI >> 1) * 2 + 1] = cvtpk(a2, a3); \
        pB[MI & 1].u[(MI >> 1) * 2 + 0] = cvtpk(b0, b1); \
        pB[MI & 1].u[(MI >> 1) * 2 + 1] = cvtpk(b2, b3); \
    }

#define QKM(KBUF, S0, S1) { \
        const char* Kb_ = (const char*)(KBUF); \
        _Pragma("unroll") \
        for (int mi = 0; mi < 4; mi++) { \
            int rK = mi * 16 + ql; \
            int sw = (rK & 7) << 4; \
            bf16x8 kf0 = *(const bf16x8*)(Kb_ + rK * 128 + ((g << 4) ^ sw)); \
            bf16x8 kf1 = *(const bf16x8*)(Kb_ + rK * 128 + ((64 + (g << 4)) ^ sw)); \
            S0[mi] = __builtin_amdgcn_mfma_f32_16x16x32_bf16(kf0, qf00, zero4, 0, 0, 0); \
            S0[mi] = __builtin_amdgcn_mfma_f32_16x16x32_bf16(kf1, qf01, S0[mi], 0, 0, 0); \
            S1[mi] = __builtin_amdgcn_mfma_f32_16x16x32_bf16(kf0, qf10, zero4, 0, 0, 0); \
            S1[mi] = __builtin_amdgcn_mfma_f32_16x16x32_bf16(kf1, qf11, S1[mi], 0, 0, 0); \
        } \
    }

#define PVM(VBUF, pA, pB) { \
        const char* Vb_ = (const char*)(VBUF); \
        bf16x8 vf0[4], vf1[4]; \
        _Pragma("unroll") \
        for (int mi = 0; mi < 4; mi++) { \
            int rV = mi * 16 + ql; \
            int sw = (rV & 7) << 4; \
            vf0[mi] = *(const bf16x8*)(Vb_ + rV * 128 + ((g << 4) ^ sw)); \
            vf1[mi] = *(const bf16x8*)(Vb_ + rV * 128 + ((64 + (g << 4)) ^ sw)); \
        } \
        _Pragma("unroll") \
        for (int mi = 0; mi < 4; mi++) { \
            po0[mi] = __builtin_amdgcn_mfma_f32_16x16x32_bf16(vf0[mi], pA[0].v, po0[mi], 0, 0, 0); \
            po0[mi] = __builtin_amdgcn_mfma_f32_16x16x32_bf16(vf1[mi], pA[1].v, po0[mi], 0, 0, 0); \
            po1[mi] = __builtin_amdgcn_mfma_f32_16x16x32_bf16(vf0[mi], pB[0].v, po1[mi], 0, 0, 0); \
            po1[mi] = __builtin_amdgcn_mfma_f32_16x16x32_bf16(vf1[mi], pB[1].v, po1[mi], 0, 0, 0); \
        } \
    }

#define ABODY(T, CUR, SC0, SC1, SN0, SN1, DO_K, DO_V) { \
        asm volatile("s_waitcnt vmcnt(0)" ::: "memory"); \
        __builtin_amdgcn_s_barrier(); \
        __builtin_amdgcn_sched_barrier(0); \
        if (DO_K) stageK(CUR, (T + 2) * 64); \
        if (DO_V) stageV(CUR ^ 1, (T + 1) * 64); \
        const char* Kb_ = (const char*)Ks[CUR ^ 1]; \
        bf16x8 kf0[4], kf1[4]; \
        _Pragma("unroll") \
        for (int mi = 0; mi < 4; mi++) { \
            int rK = mi * 16 + ql; \
            int sw = (rK & 7) << 4; \
            kf0[mi] = *(const bf16x8*)(Kb_ + rK * 128 + ((g << 4) ^ sw)); \
            kf1[mi] = *(const bf16x8*)(Kb_ + rK * 128 + ((64 + (g << 4)) ^ sw)); \
        } \
        __builtin_amdgcn_sched_group_barrier(0x100, 8, 0); \
        pfu pA[2], pB[2]; \
        float lsa = 0.f, lsb = 0.f; \
        _Pragma("unroll") \
        for (int mi = 0; mi < 4; mi++) { \
            SMCHUNK(mi, SC0, SC1, pA, pB, lsa, lsb); \
            __builtin_amdgcn_sched_group_barrier(0x2, 18, 0); \
            SN0[mi] = __builtin_amdgcn_mfma_f32_16x16x32_bf16(kf0[mi], qf00, zero4, 0, 0, 0); \
            SN0[mi] = __builtin_amdgcn_mfma_f32_16x16x32_bf16(kf1[mi], qf01, SN0[mi], 0, 0, 0); \
            SN1[mi] = __builtin_amdgcn_mfma_f32_16x16x32_bf16(kf0[mi], qf10, zero4, 0, 0, 0); \
            SN1[mi] = __builtin_amdgcn_mfma_f32_16x16x32_bf16(kf1[mi], qf11, SN1[mi], 0, 0, 0); \
            __builtin_amdgcn_sched_group_barrier(0x8, 4, 0); \
        } \
        ls0 += lsa; ls1 += lsb; \
        __builtin_amdgcn_s_setprio(1); \
        PVM(Vs[CUR], pA, pB); \
        __builtin_amdgcn_sched_group_barrier(0x100, 8, 0); \
        __builtin_amdgcn_sched_group_barrier(0x8, 16, 0); \
        __builtin_amdgcn_s_setprio(0); \
    }

    f32x4 sE0[4], sE1[4], sO0[4], sO1[4];

    // prologue: K(0),V(0),K(1) in flight; wait oldest 4 (K0+V0), then QK(0)
    stageK(0, 0); stageV(0, 0); stageK(1, 64);
    asm volatile("s_waitcnt vmcnt(2)" ::: "memory");
    __builtin_amdgcn_s_barrier();
    __builtin_amdgcn_sched_barrier(0);
    QKM(Ks[0], sE0, sE1);

    for (int t = 0; t < 62; t += 2) {
        ABODY(t, 0, sE0, sE1, sO0, sO1, 1, 1);
        ABODY(t + 1, 1, sO0, sO1, sE0, sE1, 1, 1);
    }
    ABODY(62, 0, sE0, sE1, sO0, sO1, 0, 1);

    // tail: tile 63 (scores in sO, V(63) in Vs[1])
    asm volatile("s_waitcnt vmcnt(0)" ::: "memory");
    __builtin_amdgcn_s_barrier();
    __builtin_amdgcn_sched_barrier(0);
    {
        pfu pA[2], pB[2];
        float lsa = 0.f, lsb = 0.f;
        #pragma unroll
        for (int mi = 0; mi < 4; mi++) {
            SMCHUNK(mi, sO0, sO1, pA, pB, lsa, lsb);
        }
        ls0 += lsa; ls1 += lsb;
        PVM(Vs[1], pA, pB);
    }

    // epilogue
    ls0 += __shfl_xor(ls0, 16); ls0 += __shfl_xor(ls0, 32);
    ls1 += __shfl_xor(ls1, 16); ls1 += __shfl_xor(ls1, 32);
    float inv0 = 1.0f / ls0, inv1 = 1.0f / ls1;
    unsigned short* op = O + (size_t)(b * NQ + q0 + w * 32 + ql) * INNER + h * DHEAD + (g << 2);
    #pragma unroll
    for (int mi = 0; mi < 4; mi++) {
        uint2 uu;
        uu.x = cvtpk(po0[mi][0] * inv0, po0[mi][1] * inv0);
        uu.y = cvtpk(po0[mi][2] * inv0, po0[mi][3] * inv0);
        *(uint2*)(op + mi * 16) = uu;
        uint2 vv;
        vv.x = cvtpk(po1[mi][0] * inv1, po1[mi][1] * inv1);
        vv.y = cvtpk(po1[mi][2] * inv1, po1[mi][3] * inv1);
        *(uint2*)(op + 16 * INNER + mi * 16) = vv;
    }
#undef ABODY
#undef PVM
#undef QKM
#undef SMCHUNK
}

extern "C" void kernel_launch(void* const* d_in, const int* in_sizes, int n_in,
                              void* d_out, int out_size, void* d_ws, size_t ws_size,
                              hipStream_t stream) {
    const float* x     = (const float*)d_in[0];
    const float* ctx   = (const float*)d_in[1];
    const float* w_q   = (const float*)d_in[2];
    const float* w_k   = (const float*)d_in[3];
    const float* w_v   = (const float*)d_in[4];
    const float* w_out = (const float*)d_in[5];
    const float* b_out = (const float*)d_in[6];
    float* out = (float*)d_out;

    char* ws = (char*)d_ws;
    size_t off = 0;
    auto alloc = [&](size_t bytes) { void* p = ws + off; off += (bytes + 255) & ~(size_t)255; return p; };
    unsigned short* xb  = (unsigned short*)alloc((size_t)BATCH * NQ * QDIM * 2);
    unsigned short* cb  = (unsigned short*)alloc((size_t)BATCH * NKEY * CDIM * 2);
    unsigned short* wqT = (unsigned short*)alloc((size_t)INNER * QDIM * 2);
    unsigned short* wkT = (unsigned short*)alloc((size_t)INNER * CDIM * 2);
    unsigned short* wvT = (unsigned short*)alloc((size_t)INNER * CDIM * 2);
    unsigned short* woT = (unsigned short*)alloc((size_t)ODIM * INNER * 2);
    unsigned short* Qb  = (unsigned short*)alloc((size_t)BATCH * NQ * INNER * 2);
    unsigned short* Kb  = (unsigned short*)alloc((size_t)BATCH * NKEY * INNER * 2);
    unsigned short* Vtb = (unsigned short*)alloc((size_t)INNER * BATCH * NKEY * 2);
    unsigned short* Ob  = (unsigned short*)alloc((size_t)BATCH * NQ * INNER * 2);

    // ONE prep launch: converts (z=4, grid-stride) + all 4 weight transposes (z<4)
    k_prep<<<dim3(32, 32, 5), dim3(32, 8), 0, stream>>>(
        x, xb, BATCH * NQ * QDIM / 4, ctx, cb, BATCH * NKEY * CDIM / 4,
        w_q, wqT, w_k, wkT, w_v, wvT, w_out, woT);

    // one launch: Q, K, Vt GEMMs (z-selected), 1536 blocks co-resident
    k_gemm_qkv<<<dim3(64, 8, 3), 256, 0, stream>>>(xb, cb, wqT, wkT, wvT, Qb, Kb, Vtb);

    k_attn<<<dim3(NQ / 128, BATCH * HEADS), 256, 0, stream>>>(Qb, Kb, Vtb, Ob);

    // out = O @ w_out + b_out
    k_gemm_out<<<dim3(8192 / 128, 1024 / 64), 256, 0, stream>>>(Ob, woT, out, b_out);
}

// Round 20
// 135.848 us; speedup vs baseline: 1.1836x; 1.0171x over previous
//
#include <hip/hip_runtime.h>
#include <hip/hip_bf16.h>
#include <stdint.h>

#define HEADS 8
#define DHEAD 64
#define INNER 512
#define QDIM 1024
#define CDIM 768
#define ODIM 1024
#define BATCH 2
#define NQ 4096
#define NKEY 4096

using bf16x8 = __attribute__((ext_vector_type(8))) short;
using f32x4  = __attribute__((ext_vector_type(4))) float;

__device__ __forceinline__ unsigned short f2bf(float x) {
    union { float f; unsigned u; } v; v.f = x;
    unsigned r = v.u + 0x7fffu + ((v.u >> 16) & 1u);   // RTNE
    return (unsigned short)(r >> 16);
}

__device__ __forceinline__ unsigned cvtpk(float a, float b) {
    unsigned r;
    asm("v_cvt_pk_bf16_f32 %0, %1, %2" : "=v"(r) : "v"(a), "v"(b));
    return r;
}

__device__ __forceinline__ float exp2a(float x) {
    float r;
    asm("v_exp_f32 %0, %1" : "=v"(r) : "v"(x));
    return r;
}

typedef const __attribute__((address_space(1))) unsigned int* gptr_t;
typedef __attribute__((address_space(3))) unsigned int* lptr_t;

__device__ __forceinline__ void async16(const void* g, void* l) {
    __builtin_amdgcn_global_load_lds((gptr_t)g, (lptr_t)l, 16, 0, 0);
}

#define SGB __builtin_amdgcn_sched_group_barrier

// ---------------- prep: convert x/ctx AND transpose all 4 weights, ONE launch ----------------
__global__ void k_prep(const float* __restrict__ x, unsigned short* __restrict__ xb, int n0,
                       const float* __restrict__ ctx, unsigned short* __restrict__ cb, int n1,
                       const float* __restrict__ in0, unsigned short* __restrict__ out0,
                       const float* __restrict__ in1, unsigned short* __restrict__ out1,
                       const float* __restrict__ in2, unsigned short* __restrict__ out2,
                       const float* __restrict__ in3, unsigned short* __restrict__ out3) {
    __shared__ float tile[32][33];
    const int z = blockIdx.z;
    if (z == 4) {
        int flatb = blockIdx.y * gridDim.x + blockIdx.x;
        int t = threadIdx.y * 32 + threadIdx.x;
        int i = flatb * 256 + t;
        int stride = gridDim.x * gridDim.y * 256;
        int ntot = n0 + n1;
        for (; i < ntot; i += stride) {
            const float* in = (i < n0) ? x : ctx;
            unsigned short* out = (i < n0) ? xb : cb;
            int j = (i < n0) ? i : i - n0;
            float4 v = reinterpret_cast<const float4*>(in)[j];
            ushort4 o;
            o.x = f2bf(v.x); o.y = f2bf(v.y); o.z = f2bf(v.z); o.w = f2bf(v.w);
            reinterpret_cast<ushort4*>(out)[j] = o;
        }
        return;
    }
    const int R = (z == 0) ? QDIM : (z == 3) ? INNER : CDIM;
    const int C = (z == 3) ? ODIM : INNER;
    const float* in = (z == 0) ? in0 : (z == 1) ? in1 : (z == 2) ? in2 : in3;
    unsigned short* out = (z == 0) ? out0 : (z == 1) ? out1 : (z == 2) ? out2 : out3;
    int c0 = blockIdx.x * 32, r0 = blockIdx.y * 32;
    if (c0 >= C || r0 >= R) return;
    int tx = threadIdx.x, ty = threadIdx.y;   // block (32,8)
    #pragma unroll
    for (int i = 0; i < 32; i += 8)
        tile[ty + i][tx] = in[(size_t)(r0 + ty + i) * C + c0 + tx];
    __syncthreads();
    #pragma unroll
    for (int i = 0; i < 32; i += 8)
        out[(size_t)(c0 + ty + i) * R + r0 + tx] = f2bf(tile[tx][ty + i]);
}

// ---------------- GEMM compute body, 128x64 tile (QKV; R7-proven) ----------------
#define GEMM_BODY(A_, BT_, COUT_, BIAS_, N_, KD_, SCALE_, OUTMODE_)                                  \
    {                                                                                                \
        const int tid = threadIdx.x, lane = tid & 63, w = tid >> 6;                                  \
        const int g = lane >> 4, ql = lane & 15;                                                     \
        const int wm = (w >> 1) * 64, wn = (w & 1) * 32;                                             \
        f32x4 acc[4][2] = {};                                                                        \
        const int srow = tid >> 3;                                                                   \
        const int schunk = ((tid & 7) ^ (srow & 7)) << 3;                                            \
        const unsigned short* gA = (A_) + (size_t)(m0 + srow) * (KD_) + schunk;                      \
        const unsigned short* gB = (BT_) + (size_t)(n0 + srow) * (KD_) + schunk;                     \
        auto stage = [&](int buf, int kt) {                                                          \
            char* lA = (char*)As[buf] + (w << 10);                                                   \
            char* lB = (char*)Bs[buf] + (w << 10);                                                   \
            async16(gA + kt, lA);                                                                    \
            async16(gA + kt + (size_t)32 * (KD_), lA + 4096);                                        \
            async16(gA + kt + (size_t)64 * (KD_), lA + 8192);                                        \
            async16(gA + kt + (size_t)96 * (KD_), lA + 12288);                                       \
            async16(gB + kt, lB);                                                                    \
            async16(gB + kt + (size_t)32 * (KD_), lB + 4096);                                        \
        };                                                                                           \
        stage(0, 0);                                                                                 \
        for (int kt = 0; kt < (KD_); kt += 128) {                                                    \
            asm volatile("s_waitcnt vmcnt(0)" ::: "memory");                                         \
            __builtin_amdgcn_s_barrier();                                                            \
            __builtin_amdgcn_sched_barrier(0);                                                       \
            if (kt + 64 < (KD_)) stage(1, kt + 64);                                                  \
            GCOMP(0);                                                                                \
            asm volatile("s_waitcnt vmcnt(0)" ::: "memory");                                         \
            __builtin_amdgcn_s_barrier();                                                            \
            __builtin_amdgcn_sched_barrier(0);                                                       \
            if (kt + 128 < (KD_)) stage(0, kt + 128);                                                \
            GCOMP(1);                                                                                \
        }                                                                                            \
        _Pragma("unroll")                                                                            \
        for (int mi = 0; mi < 4; mi++) {                                                             \
            _Pragma("unroll")                                                                        \
            for (int ni = 0; ni < 2; ni++) {                                                         \
                int col = n0 + wn + ni * 16 + ql;                                                    \
                _Pragma("unroll")                                                                    \
                for (int j = 0; j < 4; j++) {                                                        \
                    int row = m0 + wm + mi * 16 + (g << 2) + j;                                      \
                    float v = acc[mi][ni][j] * (SCALE_);                                             \
                    if (OUTMODE_ == 0) {                                                             \
                        ((unsigned short*)(COUT_))[(size_t)row * (N_) + col] = f2bf(v);              \
                    } else {                                                                         \
                        ((float*)(COUT_))[(size_t)row * (N_) + col] = v + (BIAS_)[col];              \
                    }                                                                                \
                }                                                                                    \
            }                                                                                        \
        }                                                                                            \
    }

#define GCOMP(BUF) { \
        _Pragma("unroll") \
        for (int kk = 0; kk < 2; kk++) { \
            bf16x8 af[4], bfr[2]; \
            _Pragma("unroll") \
            for (int mi = 0; mi < 4; mi++) { \
                int r = wm + mi * 16 + ql; \
                af[mi] = *(const bf16x8*)((const char*)As[BUF] + r * 128 + ((kk * 64 + (g << 4)) ^ ((r & 7) << 4))); \
            } \
            _Pragma("unroll") \
            for (int ni = 0; ni < 2; ni++) { \
                int r = wn + ni * 16 + ql; \
                bfr[ni] = *(const bf16x8*)((const char*)Bs[BUF] + r * 128 + ((kk * 64 + (g << 4)) ^ ((r & 7) << 4))); \
            } \
            _Pragma("unroll") \
            for (int mi = 0; mi < 4; mi++) \
                _Pragma("unroll") \
                for (int ni = 0; ni < 2; ni++) \
                    acc[mi][ni] = __builtin_amdgcn_mfma_f32_16x16x32_bf16(af[mi], bfr[ni], acc[mi][ni], 0, 0, 0); \
        } \
    }

// ---------------- merged Q/K/Vt GEMM: one dispatch, z selects operands (R18-proven) ----------------
__global__ __launch_bounds__(256) void k_gemm_qkv(const unsigned short* __restrict__ xb,
                                                  const unsigned short* __restrict__ cb,
                                                  const unsigned short* __restrict__ wqT,
                                                  const unsigned short* __restrict__ wkT,
                                                  const unsigned short* __restrict__ wvT,
                                                  unsigned short* __restrict__ Qb,
                                                  unsigned short* __restrict__ Kb,
                                                  unsigned short* __restrict__ Vtb) {
    __shared__ alignas(16) unsigned short As[2][128 * 64];
    __shared__ alignas(16) unsigned short Bs[2][64 * 64];
    const int z = blockIdx.z;
    const unsigned short* A  = (z == 0) ? xb : (z == 1) ? cb : wvT;
    const unsigned short* BT = (z == 0) ? wqT : (z == 1) ? wkT : cb;
    unsigned short* Cout     = (z == 0) ? Qb : (z == 1) ? Kb : Vtb;
    const int Kd = (z == 0) ? 1024 : 768;
    const int N  = (z == 2) ? 8192 : 512;
    const float scale = (z == 0) ? 0.1803368801111204f : 1.0f;
    int bx = blockIdx.x, by = blockIdx.y;
    if (z == 2) { int flat = by * 64 + bx; bx = flat & 3; by = flat >> 2; }
    const int m0 = bx * 128, n0 = by * 64;
    GEMM_BODY(A, BT, Cout, (const float*)nullptr, N, Kd, scale, 0);
}

// ---------------- out GEMM: 128x128 tile, BK=64 dbuf, fp32 + bias ----------------
// M=8192, N=1024, K=512. 4 waves (2Mx2N), each 64x64 (4x4 frags, 32 MFMA/K-half):
// doubles MFMA per barrier vs 128x64 -> amortizes the short-K prologue/epilogue.
// Same swizzle, same counted-wait loop; epilogue mapping = R1-proven 4x4 layout.
__global__ __launch_bounds__(256) void k_gemm_out(const unsigned short* __restrict__ A,
                                                  const unsigned short* __restrict__ BT,
                                                  float* __restrict__ Cout,
                                                  const float* __restrict__ bias) {
    __shared__ alignas(16) unsigned short As[2][128 * 64];
    __shared__ alignas(16) unsigned short Bs[2][128 * 64];
    const int tid = threadIdx.x, lane = tid & 63, w = tid >> 6;
    const int g = lane >> 4, ql = lane & 15;
    const int m0 = blockIdx.x * 128, n0 = blockIdx.y * 128;
    const int wm = (w >> 1) * 64, wn = (w & 1) * 64;
    f32x4 acc[4][4] = {};

    const int srow = tid >> 3;
    const int schunk = ((tid & 7) ^ (srow & 7)) << 3;
    const unsigned short* gA = A + (size_t)(m0 + srow) * INNER + schunk;
    const unsigned short* gB = BT + (size_t)(n0 + srow) * INNER + schunk;

    auto stage = [&](int buf, int kt) {
        char* lA = (char*)As[buf] + (w << 10);
        char* lB = (char*)Bs[buf] + (w << 10);
        async16(gA + kt, lA);
        async16(gA + kt + (size_t)32 * INNER, lA + 4096);
        async16(gA + kt + (size_t)64 * INNER, lA + 8192);
        async16(gA + kt + (size_t)96 * INNER, lA + 12288);
        async16(gB + kt, lB);
        async16(gB + kt + (size_t)32 * INNER, lB + 4096);
        async16(gB + kt + (size_t)64 * INNER, lB + 8192);
        async16(gB + kt + (size_t)96 * INNER, lB + 12288);
    };

#define GCOMP2(BUF) { \
        _Pragma("unroll") \
        for (int kk = 0; kk < 2; kk++) { \
            bf16x8 af[4], bfr[4]; \
            _Pragma("unroll") \
            for (int mi = 0; mi < 4; mi++) { \
                int r = wm + mi * 16 + ql; \
                af[mi] = *(const bf16x8*)((const char*)As[BUF] + r * 128 + ((kk * 64 + (g << 4)) ^ ((r & 7) << 4))); \
            } \
            _Pragma("unroll") \
            for (int ni = 0; ni < 4; ni++) { \
                int r = wn + ni * 16 + ql; \
                bfr[ni] = *(const bf16x8*)((const char*)Bs[BUF] + r * 128 + ((kk * 64 + (g << 4)) ^ ((r & 7) << 4))); \
            } \
            _Pragma("unroll") \
            for (int mi = 0; mi < 4; mi++) \
                _Pragma("unroll") \
                for (int ni = 0; ni < 4; ni++) \
                    acc[mi][ni] = __builtin_amdgcn_mfma_f32_16x16x32_bf16(af[mi], bfr[ni], acc[mi][ni], 0, 0, 0); \
        } \
    }

    stage(0, 0);
    for (int kt = 0; kt < INNER; kt += 128) {
        asm volatile("s_waitcnt vmcnt(0)" ::: "memory");
        __builtin_amdgcn_s_barrier();
        __builtin_amdgcn_sched_barrier(0);
        if (kt + 64 < INNER) stage(1, kt + 64);
        GCOMP2(0);
        asm volatile("s_waitcnt vmcnt(0)" ::: "memory");
        __builtin_amdgcn_s_barrier();
        __builtin_amdgcn_sched_barrier(0);
        if (kt + 128 < INNER) stage(0, kt + 128);
        GCOMP2(1);
    }
#undef GCOMP2

    #pragma unroll
    for (int mi = 0; mi < 4; mi++) {
        #pragma unroll
        for (int ni = 0; ni < 4; ni++) {
            int col = n0 + wn + ni * 16 + ql;
            #pragma unroll
            for (int j = 0; j < 4; j++) {
                int row = m0 + wm + mi * 16 + (g << 2) + j;
                Cout[(size_t)row * ODIM + col] = acc[mi][ni][j] + bias[col];
            }
        }
    }
}

// ---------------- flash attention: R7-proven body (82 us, verified) ----------------
__global__ __launch_bounds__(256, 2) void k_attn(const unsigned short* __restrict__ Q,
                                                 const unsigned short* __restrict__ K,
                                                 const unsigned short* __restrict__ Vt,
                                                 unsigned short* __restrict__ O) {
    __shared__ alignas(16) unsigned short Ks[2][64 * 64];
    __shared__ alignas(16) unsigned short Vs[2][64 * 64];
    const int tid = threadIdx.x, lane = tid & 63, w = tid >> 6;
    const int g = lane >> 4, ql = lane & 15;
    const int q0 = blockIdx.x * 128;
    const int b = blockIdx.y >> 3, h = blockIdx.y & 7;

    const unsigned short* qp = Q + (size_t)(b * NQ + q0 + w * 32 + ql) * INNER
                                 + h * DHEAD + (g << 3);
    bf16x8 qf00 = *(const bf16x8*)qp;
    bf16x8 qf01 = *(const bf16x8*)(qp + 32);
    bf16x8 qf10 = *(const bf16x8*)(qp + 16 * INNER);
    bf16x8 qf11 = *(const bf16x8*)(qp + 16 * INNER + 32);

    f32x4 po0[4] = {}, po1[4] = {};
    float ls0 = 0.f, ls1 = 0.f;
    const f32x4 zero4 = {0.f, 0.f, 0.f, 0.f};

    const int m0 = tid >> 3;
    const int rho0 = ((m0 & 28) << 1) + (m0 & 3);          // rho rows 0..31; rho(m+32)=rho(m)+4
    const int srcslot = ((tid & 7) ^ (m0 & 7)) << 3;       // swizzle pre-applied on source
    const unsigned short* gK = K + (size_t)(b * NKEY + rho0) * INNER + h * DHEAD + srcslot;
    const unsigned short* gV = Vt + (size_t)(h * DHEAD + m0) * (BATCH * NKEY) + b * NKEY + srcslot;

    auto stageK = [&](int nb, int kt) {
        char* lK = (char*)Ks[nb] + (w << 10);
        async16(gK + (size_t)kt * INNER, lK);
        async16(gK + (size_t)(kt + 4) * INNER, lK + 4096);
    };
    auto stageV = [&](int nb, int kt) {
        char* lV = (char*)Vs[nb] + (w << 10);
        async16(gV + kt, lV);
        async16(gV + kt + (size_t)32 * (BATCH * NKEY), lV + 4096);
    };

    union pfu { bf16x8 v; unsigned u[4]; };

#define SMCHUNK(MI, SC0, SC1, pA, pB, lsa, lsb) { \
        float a0 = exp2a(SC0[MI][0]), a1 = exp2a(SC0[MI][1]); \
        float a2 = exp2a(SC0[MI][2]), a3 = exp2a(SC0[MI][3]); \
        float b0 = exp2a(SC1[MI][0]), b1 = exp2a(SC1[MI][1]); \
        float b2 = exp2a(SC1[MI][2]), b3 = exp2a(SC1[MI][3]); \
        lsa += (a0 + a1) + (a2 + a3); \
        lsb += (b0 + b1) + (b2 + b3); \
        pA[MI & 1].u[(MI >> 1) * 2 + 0] = cvtpk(a0, a1); \
        pA[MI & 1].u[(MI >> 1) * 2 + 1] = cvtpk(a2, a3); \
        pB[MI & 1].u[(MI >> 1) * 2 + 0] = cvtpk(b0, b1); \
        pB[MI & 1].u[(MI >> 1) * 2 + 1] = cvtpk(b2, b3); \
    }

#define QKM(KBUF, S0, S1) { \
        const char* Kb_ = (const char*)(KBUF); \
        _Pragma("unroll") \
        for (int mi = 0; mi < 4; mi++) { \
            int rK = mi * 16 + ql; \
            int sw = (rK & 7) << 4; \
            bf16x8 kf0 = *(const bf16x8*)(Kb_ + rK * 128 + ((g << 4) ^ sw)); \
            bf16x8 kf1 = *(const bf16x8*)(Kb_ + rK * 128 + ((64 + (g << 4)) ^ sw)); \
            S0[mi] = __builtin_amdgcn_mfma_f32_16x16x32_bf16(kf0, qf00, zero4, 0, 0, 0); \
            S0[mi] = __builtin_amdgcn_mfma_f32_16x16x32_bf16(kf1, qf01, S0[mi], 0, 0, 0); \
            S1[mi] = __builtin_amdgcn_mfma_f32_16x16x32_bf16(kf0, qf10, zero4, 0, 0, 0); \
            S1[mi] = __builtin_amdgcn_mfma_f32_16x16x32_bf16(kf1, qf11, S1[mi], 0, 0, 0); \
        } \
    }

#define PVM(VBUF, pA, pB) { \
        const char* Vb_ = (const char*)(VBUF); \
        bf16x8 vf0[4], vf1[4]; \
        _Pragma("unroll") \
        for (int mi = 0; mi < 4; mi++) { \
            int rV = mi * 16 + ql; \
            int sw = (rV & 7) << 4; \
            vf0[mi] = *(const bf16x8*)(Vb_ + rV * 128 + ((g << 4) ^ sw)); \
            vf1[mi] = *(const bf16x8*)(Vb_ + rV * 128 + ((64 + (g << 4)) ^ sw)); \
        } \
        _Pragma("unroll") \
        for (int mi = 0; mi < 4; mi++) { \
            po0[mi] = __builtin_amdgcn_mfma_f32_16x16x32_bf16(vf0[mi], pA[0].v, po0[mi], 0, 0, 0); \
            po0[mi] = __builtin_amdgcn_mfma_f32_16x16x32_bf16(vf1[mi], pA[1].v, po0[mi], 0, 0, 0); \
            po1[mi] = __builtin_amdgcn_mfma_f32_16x16x32_bf16(vf0[mi], pB[0].v, po1[mi], 0, 0, 0); \
            po1[mi] = __builtin_amdgcn_mfma_f32_16x16x32_bf16(vf1[mi], pB[1].v, po1[mi], 0, 0, 0); \
        } \
    }

#define ABODY(T, CUR, SC0, SC1, SN0, SN1, DO_K, DO_V) { \
        asm volatile("s_waitcnt vmcnt(0)" ::: "memory"); \
        __builtin_amdgcn_s_barrier(); \
        __builtin_amdgcn_sched_barrier(0); \
        if (DO_K) stageK(CUR, (T + 2) * 64); \
        if (DO_V) stageV(CUR ^ 1, (T + 1) * 64); \
        const char* Kb_ = (const char*)Ks[CUR ^ 1]; \
        bf16x8 kf0[4], kf1[4]; \
        _Pragma("unroll") \
        for (int mi = 0; mi < 4; mi++) { \
            int rK = mi * 16 + ql; \
            int sw = (rK & 7) << 4; \
            kf0[mi] = *(const bf16x8*)(Kb_ + rK * 128 + ((g << 4) ^ sw)); \
            kf1[mi] = *(const bf16x8*)(Kb_ + rK * 128 + ((64 + (g << 4)) ^ sw)); \
        } \
        __builtin_amdgcn_sched_group_barrier(0x100, 8, 0); \
        pfu pA[2], pB[2]; \
        float lsa = 0.f, lsb = 0.f; \
        _Pragma("unroll") \
        for (int mi = 0; mi < 4; mi++) { \
            SMCHUNK(mi, SC0, SC1, pA, pB, lsa, lsb); \
            __builtin_amdgcn_sched_group_barrier(0x2, 18, 0); \
            SN0[mi] = __builtin_amdgcn_mfma_f32_16x16x32_bf16(kf0[mi], qf00, zero4, 0, 0, 0); \
            SN0[mi] = __builtin_amdgcn_mfma_f32_16x16x32_bf16(kf1[mi], qf01, SN0[mi], 0, 0, 0); \
            SN1[mi] = __builtin_amdgcn_mfma_f32_16x16x32_bf16(kf0[mi], qf10, zero4, 0, 0, 0); \
            SN1[mi] = __builtin_amdgcn_mfma_f32_16x16x32_bf16(kf1[mi], qf11, SN1[mi], 0, 0, 0); \
            __builtin_amdgcn_sched_group_barrier(0x8, 4, 0); \
        } \
        ls0 += lsa; ls1 += lsb; \
        __builtin_amdgcn_s_setprio(1); \
        PVM(Vs[CUR], pA, pB); \
        __builtin_amdgcn_sched_group_barrier(0x100, 8, 0); \
        __builtin_amdgcn_sched_group_barrier(0x8, 16, 0); \
        __builtin_amdgcn_s_setprio(0); \
    }

    f32x4 sE0[4], sE1[4], sO0[4], sO1[4];

    // prologue: K(0),V(0),K(1) in flight; wait oldest 4 (K0+V0), then QK(0)
    stageK(0, 0); stageV(0, 0); stageK(1, 64);
    asm volatile("s_waitcnt vmcnt(2)" ::: "memory");
    __builtin_amdgcn_s_barrier();
    __builtin_amdgcn_sched_barrier(0);
    QKM(Ks[0], sE0, sE1);

    for (int t = 0; t < 62; t += 2) {
        ABODY(t, 0, sE0, sE1, sO0, sO1, 1, 1);
        ABODY(t + 1, 1, sO0, sO1, sE0, sE1, 1, 1);
    }
    ABODY(62, 0, sE0, sE1, sO0, sO1, 0, 1);

    // tail: tile 63 (scores in sO, V(63) in Vs[1])
    asm volatile("s_waitcnt vmcnt(0)" ::: "memory");
    __builtin_amdgcn_s_barrier();
    __builtin_amdgcn_sched_barrier(0);
    {
        pfu pA[2], pB[2];
        float lsa = 0.f, lsb = 0.f;
        #pragma unroll
        for (int mi = 0; mi < 4; mi++) {
            SMCHUNK(mi, sO0, sO1, pA, pB, lsa, lsb);
        }
        ls0 += lsa; ls1 += lsb;
        PVM(Vs[1], pA, pB);
    }

    // epilogue
    ls0 += __shfl_xor(ls0, 16); ls0 += __shfl_xor(ls0, 32);
    ls1 += __shfl_xor(ls1, 16); ls1 += __shfl_xor(ls1, 32);
    float inv0 = 1.0f / ls0, inv1 = 1.0f / ls1;
    unsigned short* op = O + (size_t)(b * NQ + q0 + w * 32 + ql) * INNER + h * DHEAD + (g << 2);
    #pragma unroll
    for (int mi = 0; mi < 4; mi++) {
        uint2 uu;
        uu.x = cvtpk(po0[mi][0] * inv0, po0[mi][1] * inv0);
        uu.y = cvtpk(po0[mi][2] * inv0, po0[mi][3] * inv0);
        *(uint2*)(op + mi * 16) = uu;
        uint2 vv;
        vv.x = cvtpk(po1[mi][0] * inv1, po1[mi][1] * inv1);
        vv.y = cvtpk(po1[mi][2] * inv1, po1[mi][3] * inv1);
        *(uint2*)(op + 16 * INNER + mi * 16) = vv;
    }
#undef ABODY
#undef PVM
#undef QKM
#undef SMCHUNK
}

extern "C" void kernel_launch(void* const* d_in, const int* in_sizes, int n_in,
                              void* d_out, int out_size, void* d_ws, size_t ws_size,
                              hipStream_t stream) {
    const float* x     = (const float*)d_in[0];
    const float* ctx   = (const float*)d_in[1];
    const float* w_q   = (const float*)d_in[2];
    const float* w_k   = (const float*)d_in[3];
    const float* w_v   = (const float*)d_in[4];
    const float* w_out = (const float*)d_in[5];
    const float* b_out = (const float*)d_in[6];
    float* out = (float*)d_out;

    char* ws = (char*)d_ws;
    size_t off = 0;
    auto alloc = [&](size_t bytes) { void* p = ws + off; off += (bytes + 255) & ~(size_t)255; return p; };
    unsigned short* xb  = (unsigned short*)alloc((size_t)BATCH * NQ * QDIM * 2);
    unsigned short* cb  = (unsigned short*)alloc((size_t)BATCH * NKEY * CDIM * 2);
    unsigned short* wqT = (unsigned short*)alloc((size_t)INNER * QDIM * 2);
    unsigned short* wkT = (unsigned short*)alloc((size_t)INNER * CDIM * 2);
    unsigned short* wvT = (unsigned short*)alloc((size_t)INNER * CDIM * 2);
    unsigned short* woT = (unsigned short*)alloc((size_t)ODIM * INNER * 2);
    unsigned short* Qb  = (unsigned short*)alloc((size_t)BATCH * NQ * INNER * 2);
    unsigned short* Kb  = (unsigned short*)alloc((size_t)BATCH * NKEY * INNER * 2);
    unsigned short* Vtb = (unsigned short*)alloc((size_t)INNER * BATCH * NKEY * 2);
    unsigned short* Ob  = (unsigned short*)alloc((size_t)BATCH * NQ * INNER * 2);

    // ONE prep launch: converts (z=4, grid-stride) + all 4 weight transposes (z<4)
    k_prep<<<dim3(32, 32, 5), dim3(32, 8), 0, stream>>>(
        x, xb, BATCH * NQ * QDIM / 4, ctx, cb, BATCH * NKEY * CDIM / 4,
        w_q, wqT, w_k, wkT, w_v, wvT, w_out, woT);

    // one launch: Q, K, Vt GEMMs (z-selected), 1536 blocks co-resident
    k_gemm_qkv<<<dim3(64, 8, 3), 256, 0, stream>>>(xb, cb, wqT, wkT, wvT, Qb, Kb, Vtb);

    k_attn<<<dim3(NQ / 128, BATCH * HEADS), 256, 0, stream>>>(Qb, Kb, Vtb, Ob);

    // out = O @ w_out + b_out  (128x128 tile)
    k_gemm_out<<<dim3(8192 / 128, 1024 / 128), 256, 0, stream>>>(Ob, woT, out, b_out);
}